// Round 1
// baseline (1726.088 us; speedup 1.0000x reference)
//
#include <hip/hip_runtime.h>

#define N_NODES 8192
#define N_EDGES 131072

__device__ __forceinline__ float sigm(float x){ return 1.0f/(1.0f+__expf(-x)); }
__device__ __forceinline__ float ftanh(float x){ float e=__expf(2.0f*x); return (e-1.0f)/(e+1.0f); }
__device__ __forceinline__ float swishf(float x){ return x*sigm(x); }
__device__ __forceinline__ float leaky(float x){ return x>=0.0f? x : 0.2f*x; }
__device__ __forceinline__ float dot4(float4 a, float4 b){ return a.x*b.x+a.y*b.y+a.z*b.z+a.w*b.w; }

__device__ __forceinline__ float wave_rmax(float v){
  #pragma unroll
  for(int m=32;m;m>>=1) v=fmaxf(v,__shfl_xor(v,m));
  return v;
}
__device__ __forceinline__ float wave_rsum(float v){
  #pragma unroll
  for(int m=32;m;m>>=1) v+=__shfl_xor(v,m);
  return v;
}

// ---------------- CSR build ----------------
__global__ __launch_bounds__(256) void hist_kernel(const int* __restrict__ dst, int* __restrict__ cnt){
  int e=blockIdx.x*256+threadIdx.x;
  if(e<N_EDGES) atomicAdd(&cnt[dst[e]],1);
}

__global__ __launch_bounds__(1024) void scan_kernel(const int* __restrict__ cnt, int* __restrict__ rowptr, int* __restrict__ cursor){
  __shared__ int sums[1024];
  int t=threadIdx.x; int base=t*8;
  int local[8]; int s=0;
  #pragma unroll
  for(int i=0;i<8;++i){ local[i]=s; s+=cnt[base+i]; }
  sums[t]=s; __syncthreads();
  for(int off=1;off<1024;off<<=1){
    int v=(t>=off)?sums[t-off]:0;
    __syncthreads();
    sums[t]+=v;
    __syncthreads();
  }
  int offset=(t>0)?sums[t-1]:0;
  #pragma unroll
  for(int i=0;i<8;++i){ int v=offset+local[i]; rowptr[base+i]=v; cursor[base+i]=v; }
  if(t==1023) rowptr[N_NODES]=sums[1023];
}

__global__ __launch_bounds__(256) void scatter_kernel(const int* __restrict__ src, const int* __restrict__ dst,
                                                      int* __restrict__ cursor, int* __restrict__ csr_src){
  int e=blockIdx.x*256+threadIdx.x;
  if(e<N_EDGES){
    int slot=atomicAdd(&cursor[dst[e]],1);
    csr_src[slot]=src[e];
  }
}

// ---------------- edge-weight collapse: we[g][k] = sum_f edge_w[l][f][k]*a_edge[l][f] ----------------
// g = 2*l (gate), 2*l+1 (gnn)
__global__ __launch_bounds__(256) void we_kernel(const float* __restrict__ gate_ew, const float* __restrict__ gnn_ew,
                                                 const float* __restrict__ gate_ae, const float* __restrict__ gnn_ae,
                                                 float* __restrict__ we){
  int idx=blockIdx.x*256+threadIdx.x;
  if(idx>=12*51) return;
  int g=idx/51, k=idx%51, l=g>>1;
  const float* ew = (g&1)? gnn_ew + l*128*51 : gate_ew + l*128*51;
  const float* ae = (g&1)? gnn_ae + l*128    : gate_ae + l*128;
  float s=0.f;
  for(int f=0;f<128;++f) s+=ew[f*51+k]*ae[f];
  we[idx]=s;
}

// gsc[g][n] = sum_k we[g][k]*u[n][k] (k<50) + we[g][50]*pos_x[n]
__global__ __launch_bounds__(128) void gsc_kernel(const float* __restrict__ u, const float* __restrict__ pos,
                                                  const float* __restrict__ we, float* __restrict__ gsc){
  int n=blockIdx.x*128+threadIdx.x;
  float uv[50];
  #pragma unroll
  for(int k=0;k<50;++k) uv[k]=u[n*50+k];
  float px=pos[n*2+1]*(1.0f/16.0f);
  for(int g=0;g<12;++g){
    const float* w=we+g*51;
    float s=w[50]*px;
    #pragma unroll
    for(int k=0;k<50;++k) s+=w[k]*uv[k];
    gsc[g*N_NODES+n]=s;
  }
}

// ---------------- LEM scan (25 steps) + output MLP, fused ----------------
// 256 threads: f = tid&127 owns hidden feature f; half = tid>>7 owns 8 of the block's 16 nodes.
__global__ __launch_bounds__(256) void lem_mlp_kernel(
    const float* __restrict__ u, const float* __restrict__ pos,
    const float* __restrict__ Wi, const float* __restrict__ bi,   // [512][4],[512]
    const float* __restrict__ Wh, const float* __restrict__ bh,   // [384][128],[384]
    const float* __restrict__ Wz, const float* __restrict__ bz,   // [128][128],[128]
    const float* __restrict__ W1, const float* __restrict__ b1,
    const float* __restrict__ W2, const float* __restrict__ b2,
    float* __restrict__ hout)
{
  __shared__ float y_lds[16][128];
  __shared__ float z_lds[16][128];
  __shared__ float u_lds[16][50];
  __shared__ float px_s[16], pt_s[16];
  const int tid=threadIdx.x;
  const int f=tid&127;
  const int nb=(tid>>7)*8;
  const int n0=blockIdx.x*16;

  for(int i=tid;i<16*50;i+=256) u_lds[i/50][i%50]=u[n0*50+i];
  if(tid<16){ px_s[tid]=pos[(n0+tid)*2+1]*(1.0f/16.0f); pt_s[tid]=pos[(n0+tid)*2+0]*0.25f; }

  float yreg[8], zreg[8];
  #pragma unroll
  for(int n=0;n<8;++n){ yreg[n]=0.f; zreg[n]=0.f; y_lds[nb+n][f]=0.f; }

  const float bi1=bi[f], bi2=bi[128+f], bi3=bi[256+f], bi4=bi[384+f];
  const float bh1=bh[f], bh2=bh[128+f], bh3=bh[256+f], bzf=bz[f];
  const float4 wi1=*(const float4*)(Wi+4*f),       wi2=*(const float4*)(Wi+4*(128+f));
  const float4 wi3=*(const float4*)(Wi+4*(256+f)), wi4=*(const float4*)(Wi+4*(384+f));
  const float4* __restrict__ wh1=(const float4*)(Wh + f*128);
  const float4* __restrict__ wh2=(const float4*)(Wh + (128+f)*128);
  const float4* __restrict__ wh3=(const float4*)(Wh + (256+f)*128);
  const float4* __restrict__ wzp=(const float4*)(Wz + f*128);
  __syncthreads();

  for(int t=0;t<25;++t){
    float a1[8],a2[8],a3[8];
    #pragma unroll
    for(int n=0;n<8;++n){a1[n]=0.f;a2[n]=0.f;a3[n]=0.f;}
    for(int k=0;k<32;++k){
      float4 w1=wh1[k], w2=wh2[k], w3=wh3[k];
      #pragma unroll
      for(int n=0;n<8;++n){
        float4 yv=*(const float4*)&y_lds[nb+n][k*4];
        a1[n]+=dot4(w1,yv); a2[n]+=dot4(w2,yv); a3[n]+=dot4(w3,yv);
      }
    }
    float i4s[8], msbs[8];
    #pragma unroll
    for(int n=0;n<8;++n){
      float px=px_s[nb+n], u0=u_lds[nb+n][t], u1=u_lds[nb+n][25+t], tsv=pt_s[nb+n]+0.04f*(t+1);
      float i1=bi1+wi1.x*px+wi1.y*u0+wi1.z*u1+wi1.w*tsv;
      float i2=bi2+wi2.x*px+wi2.y*u0+wi2.z*u1+wi2.w*tsv;
      float i3=bi3+wi3.x*px+wi3.y*u0+wi3.z*u1+wi3.w*tsv;
      float i4=bi4+wi4.x*px+wi4.y*u0+wi4.z*u1+wi4.w*tsv;
      float msb=sigm(i1+a1[n]+bh1);
      float ms =sigm(i2+a2[n]+bh2);
      float zn=(1.0f-ms)*zreg[n]+ms*ftanh(i3+a3[n]+bh3);
      zreg[n]=zn; z_lds[nb+n][f]=zn;
      i4s[n]=i4; msbs[n]=msb;
    }
    __syncthreads();
    float a4[8];
    #pragma unroll
    for(int n=0;n<8;++n) a4[n]=0.f;
    for(int k=0;k<32;++k){
      float4 w=wzp[k];
      #pragma unroll
      for(int n=0;n<8;++n){ float4 zv=*(const float4*)&z_lds[nb+n][k*4]; a4[n]+=dot4(w,zv); }
    }
    #pragma unroll
    for(int n=0;n<8;++n){
      float yn=(1.0f-msbs[n])*yreg[n]+msbs[n]*ftanh(a4[n]+bzf+i4s[n]);
      yreg[n]=yn; y_lds[nb+n][f]=yn;
    }
    __syncthreads();
  }

  // MLP: h = swish(swish(y W1^T + b1) W2^T + b2)
  {
    const float4* w1p=(const float4*)(W1 + f*128);
    float acc[8];
    #pragma unroll
    for(int n=0;n<8;++n) acc[n]=0.f;
    for(int k=0;k<32;++k){
      float4 w=w1p[k];
      #pragma unroll
      for(int n=0;n<8;++n){ float4 yv=*(const float4*)&y_lds[nb+n][k*4]; acc[n]+=dot4(w,yv); }
    }
    float b1f=b1[f];
    #pragma unroll
    for(int n=0;n<8;++n) z_lds[nb+n][f]=swishf(acc[n]+b1f);
  }
  __syncthreads();
  {
    const float4* w2p=(const float4*)(W2 + f*128);
    float acc[8];
    #pragma unroll
    for(int n=0;n<8;++n) acc[n]=0.f;
    for(int k=0;k<32;++k){
      float4 w=w2p[k];
      #pragma unroll
      for(int n=0;n<8;++n){ float4 zv=*(const float4*)&z_lds[nb+n][k*4]; acc[n]+=dot4(w,zv); }
    }
    float b2f=b2[f];
    #pragma unroll
    for(int n=0;n<8;++n) hout[(n0+nb+n)*128+f]=swishf(acc[n]+b2f);
  }
}

// ---------------- per-layer GAT transform (both gate & gnn) ----------------
// xt_g/xt_m = h @ W^T; ssg[n]=xt_g[n].a_src + g_gate[n]; sdg[n]=xt_g[n].a_dst - g_gate[n]; same for gnn.
__global__ __launch_bounds__(128) void gat_transform(
    const float* __restrict__ h,
    const float* __restrict__ Wg, const float* __restrict__ Wm,
    const float* __restrict__ att_sg, const float* __restrict__ att_dg,
    const float* __restrict__ att_sm, const float* __restrict__ att_dm,
    const float* __restrict__ gsc_g, const float* __restrict__ gsc_m,
    float* __restrict__ xt_g, float* __restrict__ xt_m,
    float* __restrict__ ssg, float* __restrict__ sdg,
    float* __restrict__ ssm, float* __restrict__ sdm)
{
  __shared__ float h_lds[16][128];
  __shared__ float wred[2][4];
  const int f=threadIdx.x;
  const int n0=blockIdx.x*16;
  for(int i=f;i<16*128;i+=128) ((float*)h_lds)[i]=h[n0*128+i];
  __syncthreads();
  float ag[16], am[16];
  #pragma unroll
  for(int n=0;n<16;++n){ag[n]=0.f;am[n]=0.f;}
  const float4* wgp=(const float4*)(Wg + f*128);
  const float4* wmp=(const float4*)(Wm + f*128);
  for(int k=0;k<32;++k){
    float4 wg=wgp[k], wm=wmp[k];
    #pragma unroll
    for(int n=0;n<16;++n){
      float4 hv=*(const float4*)&h_lds[n][k*4];
      ag[n]+=dot4(wg,hv); am[n]+=dot4(wm,hv);
    }
  }
  #pragma unroll
  for(int n=0;n<16;++n){
    xt_g[(n0+n)*128+f]=ag[n];
    xt_m[(n0+n)*128+f]=am[n];
  }
  const float csg=att_sg[f], cdg=att_dg[f], csm=att_sm[f], cdm=att_dm[f];
  const int lane=f&63, wid=f>>6;
  for(int n=0;n<16;++n){
    float vx=ag[n]*csg, vy=ag[n]*cdg, vz=am[n]*csm, vw=am[n]*cdm;
    #pragma unroll
    for(int m=32;m;m>>=1){
      vx+=__shfl_xor(vx,m); vy+=__shfl_xor(vy,m);
      vz+=__shfl_xor(vz,m); vw+=__shfl_xor(vw,m);
    }
    if(lane==0){ wred[wid][0]=vx; wred[wid][1]=vy; wred[wid][2]=vz; wred[wid][3]=vw; }
    __syncthreads();
    if(f==0){
      float gg=gsc_g[n0+n], gm=gsc_m[n0+n];
      ssg[n0+n]=wred[0][0]+wred[1][0]+gg;
      sdg[n0+n]=wred[0][1]+wred[1][1]-gg;
      ssm[n0+n]=wred[0][2]+wred[1][2]+gm;
      sdm[n0+n]=wred[0][3]+wred[1][3]-gm;
    }
    __syncthreads();
  }
}

// ---------------- per-layer dual GAT aggregate + gated h update (in-place) ----------------
// one wave per node; lane owns features lane and lane+64
__global__ __launch_bounds__(256) void gat_aggregate(
    const int* __restrict__ rowptr, const int* __restrict__ csr_src,
    const float* __restrict__ xt_g, const float* __restrict__ xt_m,
    const float* __restrict__ ssg, const float* __restrict__ sdg,
    const float* __restrict__ ssm, const float* __restrict__ sdm,
    const float* __restrict__ bias_g, const float* __restrict__ bias_m,
    float* __restrict__ h)
{
  const int lane=threadIdx.x&63;
  const int n=blockIdx.x*4+(threadIdx.x>>6);
  const int s0=rowptr[n], s1=rowptr[n+1];
  const int deg=s1-s0;
  const float bg=sdg[n], bm=sdm[n];
  float mg=-1e30f, mm=-1e30f;
  for(int i=lane;i<deg;i+=64){
    int s=csr_src[s0+i];
    mg=fmaxf(mg,leaky(ssg[s]+bg));
    mm=fmaxf(mm,leaky(ssm[s]+bm));
  }
  mg=wave_rmax(mg); mm=wave_rmax(mm);
  float dg=0.f,dm=0.f,ag0=0.f,ag1=0.f,am0=0.f,am1=0.f;
  for(int c=0;c<deg;c+=64){
    int i=c+lane; int s=0; float eg=0.f,em=0.f;
    if(i<deg){
      s=csr_src[s0+i];
      eg=__expf(leaky(ssg[s]+bg)-mg);
      em=__expf(leaky(ssm[s]+bm)-mm);
      dg+=eg; dm+=em;
    }
    int cntc=min(64,deg-c);
    for(int j=0;j<cntc;++j){
      int ss=__shfl(s,j);
      float egj=__shfl(eg,j), emj=__shfl(em,j);
      const float* xg=xt_g+ss*128;
      const float* xm=xt_m+ss*128;
      ag0+=egj*xg[lane];    ag1+=egj*xg[64+lane];
      am0+=emj*xm[lane];    am1+=emj*xm[64+lane];
    }
  }
  dg=wave_rsum(dg); dm=wave_rsum(dm);
  float rg=1.0f/(dg+1e-16f), rm=1.0f/(dm+1e-16f);
  float og0=ag0*rg+bias_g[lane], og1=ag1*rg+bias_g[64+lane];
  float om0=am0*rm+bias_m[lane], om1=am1*rm+bias_m[64+lane];
  float tau0=sigm(og0), tau1=sigm(og1);
  float msg0=swishf(om0), msg1=swishf(om1);
  float h0=h[n*128+lane], h1=h[n*128+64+lane];
  h[n*128+lane]   =(1.0f-tau0)*h0+tau0*msg0;
  h[n*128+64+lane]=(1.0f-tau1)*h1+tau1*msg1;
}

// ---------------- decoder: dbl MLP + conv1d x2 + residual ----------------
__global__ __launch_bounds__(256) void decoder_kernel(
    const float* __restrict__ h, const float* __restrict__ u,
    const float* __restrict__ Wd, const float* __restrict__ bd,
    const float* __restrict__ w1, const float* __restrict__ b1,
    const float* __restrict__ w2, const float* __restrict__ b2,
    float* __restrict__ out)
{
  __shared__ float h_lds[8][128];
  __shared__ float h2[8][2][128];
  __shared__ float c1[8][8][38];
  __shared__ float w1s[256], w2s[224], b1s[8], b2s[2];
  const int tid=threadIdx.x;
  const int n0=blockIdx.x*8;
  for(int i=tid;i<8*128;i+=256) ((float*)h_lds)[i]=h[n0*128+i];
  w1s[tid]=w1[tid];
  if(tid<224) w2s[tid]=w2[tid];
  if(tid<8) b1s[tid]=b1[tid];
  if(tid<2) b2s[tid]=b2[tid];
  __syncthreads();
  {
    const float4* wp=(const float4*)(Wd + tid*128);
    float acc[8];
    #pragma unroll
    for(int n=0;n<8;++n)acc[n]=0.f;
    for(int k=0;k<32;++k){
      float4 w=wp[k];
      #pragma unroll
      for(int n=0;n<8;++n){ float4 hv=*(const float4*)&h_lds[n][k*4]; acc[n]+=dot4(w,hv); }
    }
    float bdv=bd[tid];
    int ch=tid>>7, p=tid&127;
    #pragma unroll
    for(int n=0;n<8;++n) h2[n][ch][p]=swishf(acc[n]+bdv);
  }
  __syncthreads();
  for(int idx=tid; idx<8*8*38; idx+=256){
    int n=idx/(8*38); int r=idx%(8*38); int oc=r/38, p=r%38;
    float acc=b1s[oc];
    const float* ww=&w1s[oc*32];
    #pragma unroll
    for(int ic=0;ic<2;++ic)
      #pragma unroll
      for(int k=0;k<16;++k) acc+=ww[ic*16+k]*h2[n][ic][3*p+k];
    c1[n][oc][p]=swishf(acc);
  }
  __syncthreads();
  for(int idx=tid; idx<8*2*25; idx+=256){
    int n=idx/50; int r=idx%50; int oc=r/25, p=r%25;
    float acc=b2s[oc];
    const float* ww=&w2s[oc*112];
    #pragma unroll
    for(int ic=0;ic<8;++ic)
      #pragma unroll
      for(int k=0;k<14;++k) acc+=ww[ic*14+k]*c1[n][ic][p+k];
    int col=oc*25+p;
    out[(n0+n)*50+col]=u[(n0+n)*50+col]+0.04f*(float)(p+1)*acc;
  }
}

extern "C" void kernel_launch(void* const* d_in, const int* in_sizes, int n_in,
                              void* d_out, int out_size, void* d_ws, size_t ws_size,
                              hipStream_t stream)
{
  const float* u          =(const float*)d_in[0];
  const float* pos        =(const float*)d_in[1];
  const int*   ei         =(const int*)d_in[2];
  const float* lem_inp_w  =(const float*)d_in[3];
  const float* lem_inp_b  =(const float*)d_in[4];
  const float* lem_hid_w  =(const float*)d_in[5];
  const float* lem_hid_b  =(const float*)d_in[6];
  const float* lem_z_w    =(const float*)d_in[7];
  const float* lem_z_b    =(const float*)d_in[8];
  const float* mlp1_w     =(const float*)d_in[9];
  const float* mlp1_b     =(const float*)d_in[10];
  const float* mlp2_w     =(const float*)d_in[11];
  const float* mlp2_b     =(const float*)d_in[12];
  const float* gnn_lin_w  =(const float*)d_in[13];
  const float* gnn_edge_w =(const float*)d_in[14];
  const float* gnn_att_src=(const float*)d_in[15];
  const float* gnn_att_dst=(const float*)d_in[16];
  const float* gnn_att_edge=(const float*)d_in[17];
  const float* gnn_bias   =(const float*)d_in[18];
  const float* gate_lin_w =(const float*)d_in[19];
  const float* gate_edge_w=(const float*)d_in[20];
  const float* gate_att_src=(const float*)d_in[21];
  const float* gate_att_dst=(const float*)d_in[22];
  const float* gate_att_edge=(const float*)d_in[23];
  const float* gate_bias  =(const float*)d_in[24];
  const float* dbl_w      =(const float*)d_in[25];
  const float* dbl_b      =(const float*)d_in[26];
  const float* conv1_w    =(const float*)d_in[27];
  const float* conv1_b    =(const float*)d_in[28];
  const float* conv2_w    =(const float*)d_in[29];
  const float* conv2_b    =(const float*)d_in[30];
  float* out=(float*)d_out;

  char* ws=(char*)d_ws;
  size_t off=0;
  auto alloc=[&](size_t bytes)->char*{ char* p=ws+off; off+=(bytes+255)&~(size_t)255; return p; };
  float* h    =(float*)alloc((size_t)N_NODES*128*4);
  float* xt_g =(float*)alloc((size_t)N_NODES*128*4);
  float* xt_m =(float*)alloc((size_t)N_NODES*128*4);
  float* ssg  =(float*)alloc(N_NODES*4);
  float* sdg  =(float*)alloc(N_NODES*4);
  float* ssm  =(float*)alloc(N_NODES*4);
  float* sdm  =(float*)alloc(N_NODES*4);
  float* gsc  =(float*)alloc((size_t)12*N_NODES*4);
  float* wearr=(float*)alloc(12*51*4);
  int* cnt    =(int*)alloc(N_NODES*4);
  int* rowptr =(int*)alloc((N_NODES+8)*4);
  int* cursor =(int*)alloc(N_NODES*4);
  int* csrsrc =(int*)alloc((size_t)N_EDGES*4);

  const int* src=ei;
  const int* dst=ei+N_EDGES;

  hipMemsetAsync(cnt,0,N_NODES*4,stream);
  hist_kernel<<<N_EDGES/256,256,0,stream>>>(dst,cnt);
  scan_kernel<<<1,1024,0,stream>>>(cnt,rowptr,cursor);
  scatter_kernel<<<N_EDGES/256,256,0,stream>>>(src,dst,cursor,csrsrc);
  we_kernel<<<3,256,0,stream>>>(gate_edge_w,gnn_edge_w,gate_att_edge,gnn_att_edge,wearr);
  gsc_kernel<<<N_NODES/128,128,0,stream>>>(u,pos,wearr,gsc);
  lem_mlp_kernel<<<N_NODES/16,256,0,stream>>>(u,pos,lem_inp_w,lem_inp_b,lem_hid_w,lem_hid_b,
                                              lem_z_w,lem_z_b,mlp1_w,mlp1_b,mlp2_w,mlp2_b,h);
  for(int l=0;l<6;++l){
    gat_transform<<<N_NODES/16,128,0,stream>>>(h,
      gate_lin_w+(size_t)l*128*128, gnn_lin_w+(size_t)l*128*128,
      gate_att_src+l*128, gate_att_dst+l*128,
      gnn_att_src+l*128, gnn_att_dst+l*128,
      gsc+(size_t)(2*l)*N_NODES, gsc+(size_t)(2*l+1)*N_NODES,
      xt_g, xt_m, ssg, sdg, ssm, sdm);
    gat_aggregate<<<N_NODES/4,256,0,stream>>>(rowptr,csrsrc,xt_g,xt_m,ssg,sdg,ssm,sdm,
      gate_bias+l*128, gnn_bias+l*128, h);
  }
  decoder_kernel<<<N_NODES/8,256,0,stream>>>(h,u,dbl_w,dbl_b,conv1_w,conv1_b,conv2_w,conv2_b,out);
}

// Round 2
// 666.847 us; speedup vs baseline: 2.5884x; 2.5884x over previous
//
#include <hip/hip_runtime.h>

#define N_NODES 8192
#define N_EDGES 131072

using short8 = __attribute__((ext_vector_type(8))) short;
using f32x4  = __attribute__((ext_vector_type(4))) float;

__device__ __forceinline__ float rcpf(float x){ return __builtin_amdgcn_rcpf(x); }
__device__ __forceinline__ float sigm(float x){ return rcpf(1.0f+__expf(-x)); }
__device__ __forceinline__ float ftanh(float x){ float e=__expf(2.0f*x); return (e-1.0f)*rcpf(e+1.0f); }
__device__ __forceinline__ float swishf(float x){ return x*sigm(x); }
__device__ __forceinline__ float leaky(float x){ return x>=0.0f? x : 0.2f*x; }
__device__ __forceinline__ float dot4(float4 a, float4 b){ return a.x*b.x+a.y*b.y+a.z*b.z+a.w*b.w; }
__device__ __forceinline__ short f2bf(float x){
  unsigned u=__float_as_uint(x);
  unsigned r=(u + 0x7fffu + ((u>>16)&1u))>>16;
  return (short)r;
}

__device__ __forceinline__ float wave_rmax(float v){
  #pragma unroll
  for(int m=32;m;m>>=1) v=fmaxf(v,__shfl_xor(v,m));
  return v;
}
__device__ __forceinline__ float wave_rsum(float v){
  #pragma unroll
  for(int m=32;m;m>>=1) v+=__shfl_xor(v,m);
  return v;
}

// ---------------- CSR build ----------------
__global__ __launch_bounds__(256) void hist_kernel(const int* __restrict__ dst, int* __restrict__ cnt){
  int e=blockIdx.x*256+threadIdx.x;
  if(e<N_EDGES) atomicAdd(&cnt[dst[e]],1);
}

__global__ __launch_bounds__(1024) void scan_kernel(const int* __restrict__ cnt, int* __restrict__ rowptr, int* __restrict__ cursor){
  __shared__ int sums[1024];
  int t=threadIdx.x; int base=t*8;
  int local[8]; int s=0;
  #pragma unroll
  for(int i=0;i<8;++i){ local[i]=s; s+=cnt[base+i]; }
  sums[t]=s; __syncthreads();
  for(int off=1;off<1024;off<<=1){
    int v=(t>=off)?sums[t-off]:0;
    __syncthreads();
    sums[t]+=v;
    __syncthreads();
  }
  int offset=(t>0)?sums[t-1]:0;
  #pragma unroll
  for(int i=0;i<8;++i){ int v=offset+local[i]; rowptr[base+i]=v; cursor[base+i]=v; }
  if(t==1023) rowptr[N_NODES]=sums[1023];
}

__global__ __launch_bounds__(256) void scatter_kernel(const int* __restrict__ src, const int* __restrict__ dst,
                                                      int* __restrict__ cursor, int* __restrict__ csr_src){
  int e=blockIdx.x*256+threadIdx.x;
  if(e<N_EDGES){
    int slot=atomicAdd(&cursor[dst[e]],1);
    csr_src[slot]=src[e];
  }
}

// ---------------- fp32 -> bf16 weight conversion ----------------
__global__ __launch_bounds__(256) void tobf16_kernel(const float* __restrict__ a, short* __restrict__ o, int n){
  int i=blockIdx.x*256+threadIdx.x;
  if(i<n) o[i]=f2bf(a[i]);
}

// ---------------- edge-weight collapse ----------------
__global__ __launch_bounds__(256) void we_kernel(const float* __restrict__ gate_ew, const float* __restrict__ gnn_ew,
                                                 const float* __restrict__ gate_ae, const float* __restrict__ gnn_ae,
                                                 float* __restrict__ we){
  int idx=blockIdx.x*256+threadIdx.x;
  if(idx>=12*51) return;
  int g=idx/51, k=idx%51, l=g>>1;
  const float* ew = (g&1)? gnn_ew + l*128*51 : gate_ew + l*128*51;
  const float* ae = (g&1)? gnn_ae + l*128    : gate_ae + l*128;
  float s=0.f;
  for(int f=0;f<128;++f) s+=ew[f*51+k]*ae[f];
  we[idx]=s;
}

__global__ __launch_bounds__(128) void gsc_kernel(const float* __restrict__ u, const float* __restrict__ pos,
                                                  const float* __restrict__ we, float* __restrict__ gsc){
  int n=blockIdx.x*128+threadIdx.x;
  float uv[50];
  #pragma unroll
  for(int k=0;k<50;++k) uv[k]=u[n*50+k];
  float px=pos[n*2+1]*(1.0f/16.0f);
  for(int g=0;g<12;++g){
    const float* w=we+g*51;
    float s=w[50]*px;
    #pragma unroll
    for(int k=0;k<50;++k) s+=w[k]*uv[k];
    gsc[g*N_NODES+n]=s;
  }
}

// ---------------- LEM scan (MFMA) + output MLP, fused ----------------
// 512 threads = 8 waves, 16 nodes/block.
// MFMA: wave w owns Wh col-tiles {3w,3w+1,3w+2} and Wz/W1/W2 col-tile w.
// Elementwise: f=tid&127, group g=tid>>7 owns nodes 4g..4g+3.
__global__ __launch_bounds__(512,2) void lem_mfma_kernel(
    const float* __restrict__ u, const float* __restrict__ pos,
    const float* __restrict__ Wi, const float* __restrict__ bi,
    const short* __restrict__ whb, const float* __restrict__ bh,
    const short* __restrict__ wzb, const float* __restrict__ bz,
    const short* __restrict__ w1b, const float* __restrict__ b1,
    const short* __restrict__ w2b, const float* __restrict__ b2,
    float* __restrict__ hout)
{
  __shared__ float hh[16*385];
  __shared__ short y16[16*128];
  __shared__ short z16[16*128];
  __shared__ float u_s[16*50];
  __shared__ float px_s[16], pt_s[16];

  const int tid=threadIdx.x;
  const int lane=tid&63;
  const int w=tid>>6;
  const int n0=blockIdx.x*16;
  const int r16=lane&15, kq=lane>>4;

  for(int i=tid;i<16*50;i+=512) u_s[i]=u[n0*50+i];
  if(tid<16){ px_s[tid]=pos[(n0+tid)*2+1]*(1.0f/16.0f); pt_s[tid]=pos[(n0+tid)*2+0]*0.25f; }
  for(int i=tid;i<16*128;i+=512) y16[i]=0;

  const int f=tid&127;
  const int g=tid>>7;
  const float4 wi1=*(const float4*)(Wi+4*f);
  const float4 wi2=*(const float4*)(Wi+4*(128+f));
  const float4 wi3=*(const float4*)(Wi+4*(256+f));
  const float4 wi4=*(const float4*)(Wi+4*(384+f));
  const float bi1=bi[f], bi2=bi[128+f], bi3=bi[256+f], bi4=bi[384+f];
  const float bh1=bh[f], bh2=bh[128+f], bh3=bh[256+f], bzf=bz[f];

  short8 whf[3][4];
  #pragma unroll
  for(int t3=0;t3<3;++t3)
    #pragma unroll
    for(int kk=0;kk<4;++kk)
      whf[t3][kk]=*(const short8*)(whb + (w*48+t3*16+r16)*128 + kk*32 + kq*8);
  short8 wzf[4];
  #pragma unroll
  for(int kk=0;kk<4;++kk)
    wzf[kk]=*(const short8*)(wzb + (w*16+r16)*128 + kk*32 + kq*8);

  float yreg[4]={0.f,0.f,0.f,0.f}, zreg[4]={0.f,0.f,0.f,0.f};
  float msb[4], i4s[4];
  __syncthreads();

  for(int t=0;t<25;++t){
    // Phase A: hh = y @ Wh^T  (16x384)
    {
      f32x4 a0={0.f,0.f,0.f,0.f}, a1=a0, a2=a0;
      #pragma unroll
      for(int kk=0;kk<4;++kk){
        short8 ya=*(const short8*)&y16[r16*128 + ((kk*32+kq*8) ^ ((r16&7)<<3))];
        a0=__builtin_amdgcn_mfma_f32_16x16x32_bf16(ya,whf[0][kk],a0,0,0,0);
        a1=__builtin_amdgcn_mfma_f32_16x16x32_bf16(ya,whf[1][kk],a1,0,0,0);
        a2=__builtin_amdgcn_mfma_f32_16x16x32_bf16(ya,whf[2][kk],a2,0,0,0);
      }
      #pragma unroll
      for(int r=0;r<4;++r){
        int row=kq*4+r;
        hh[row*385 + w*48 +      r16]=a0[r];
        hh[row*385 + w*48 + 16 + r16]=a1[r];
        hh[row*385 + w*48 + 32 + r16]=a2[r];
      }
    }
    __syncthreads();
    // Phase B: elementwise z update
    #pragma unroll
    for(int j=0;j<4;++j){
      int n=4*g+j;
      float px=px_s[n], u0=u_s[n*50+t], u1=u_s[n*50+25+t], tsv=pt_s[n]+0.04f*(float)(t+1);
      float i1=bi1+wi1.x*px+wi1.y*u0+wi1.z*u1+wi1.w*tsv;
      float i2=bi2+wi2.x*px+wi2.y*u0+wi2.z*u1+wi2.w*tsv;
      float i3=bi3+wi3.x*px+wi3.y*u0+wi3.z*u1+wi3.w*tsv;
      float i4=bi4+wi4.x*px+wi4.y*u0+wi4.z*u1+wi4.w*tsv;
      float h1=hh[n*385+f], h2=hh[n*385+128+f], h3=hh[n*385+256+f];
      msb[j]=sigm(i1+h1+bh1);
      float ms=sigm(i2+h2+bh2);
      float zn=(1.0f-ms)*zreg[j]+ms*ftanh(i3+h3+bh3);
      zreg[j]=zn; i4s[j]=i4;
      z16[n*128 + (f ^ ((n&7)<<3))]=f2bf(zn);
    }
    __syncthreads();
    // Phase C: zw = z @ Wz^T -> hh cols 0..127
    {
      f32x4 a={0.f,0.f,0.f,0.f};
      #pragma unroll
      for(int kk=0;kk<4;++kk){
        short8 za=*(const short8*)&z16[r16*128 + ((kk*32+kq*8) ^ ((r16&7)<<3))];
        a=__builtin_amdgcn_mfma_f32_16x16x32_bf16(za,wzf[kk],a,0,0,0);
      }
      #pragma unroll
      for(int r=0;r<4;++r) hh[(kq*4+r)*385 + w*16 + r16]=a[r];
    }
    __syncthreads();
    // Phase D: y update
    #pragma unroll
    for(int j=0;j<4;++j){
      int n=4*g+j;
      float zw=hh[n*385+f];
      float yn=(1.0f-msb[j])*yreg[j]+msb[j]*ftanh(zw+bzf+i4s[j]);
      yreg[j]=yn;
      y16[n*128 + (f ^ ((n&7)<<3))]=f2bf(yn);
    }
    __syncthreads();
  }

  // MLP1: t1 = swish(y @ W1^T + b1) -> z16 (bf16, swizzled)
  {
    short8 wf[4];
    #pragma unroll
    for(int kk=0;kk<4;++kk)
      wf[kk]=*(const short8*)(w1b + (w*16+r16)*128 + kk*32 + kq*8);
    float b1v=b1[w*16+r16];
    f32x4 a={0.f,0.f,0.f,0.f};
    #pragma unroll
    for(int kk=0;kk<4;++kk){
      short8 ya=*(const short8*)&y16[r16*128 + ((kk*32+kq*8) ^ ((r16&7)<<3))];
      a=__builtin_amdgcn_mfma_f32_16x16x32_bf16(ya,wf[kk],a,0,0,0);
    }
    #pragma unroll
    for(int r=0;r<4;++r){
      int row=kq*4+r;
      float v=swishf(a[r]+b1v);
      z16[row*128 + ((w*16+r16) ^ ((row&7)<<3))]=f2bf(v);
    }
  }
  __syncthreads();
  // MLP2: h = swish(t1 @ W2^T + b2) -> global
  {
    short8 wf[4];
    #pragma unroll
    for(int kk=0;kk<4;++kk)
      wf[kk]=*(const short8*)(w2b + (w*16+r16)*128 + kk*32 + kq*8);
    float b2v=b2[w*16+r16];
    f32x4 a={0.f,0.f,0.f,0.f};
    #pragma unroll
    for(int kk=0;kk<4;++kk){
      short8 za=*(const short8*)&z16[r16*128 + ((kk*32+kq*8) ^ ((r16&7)<<3))];
      a=__builtin_amdgcn_mfma_f32_16x16x32_bf16(za,wf[kk],a,0,0,0);
    }
    #pragma unroll
    for(int r=0;r<4;++r){
      int row=kq*4+r;
      hout[(n0+row)*128 + w*16 + r16]=swishf(a[r]+b2v);
    }
  }
}

// ---------------- per-layer GAT transform (both gate & gnn) ----------------
__global__ __launch_bounds__(128) void gat_transform(
    const float* __restrict__ h,
    const float* __restrict__ Wg, const float* __restrict__ Wm,
    const float* __restrict__ att_sg, const float* __restrict__ att_dg,
    const float* __restrict__ att_sm, const float* __restrict__ att_dm,
    const float* __restrict__ gsc_g, const float* __restrict__ gsc_m,
    float* __restrict__ xt_g, float* __restrict__ xt_m,
    float* __restrict__ ssg, float* __restrict__ sdg,
    float* __restrict__ ssm, float* __restrict__ sdm)
{
  __shared__ float h_lds[16][128];
  __shared__ float wred[2][4];
  const int f=threadIdx.x;
  const int n0=blockIdx.x*16;
  for(int i=f;i<16*128;i+=128) ((float*)h_lds)[i]=h[n0*128+i];
  __syncthreads();
  float ag[16], am[16];
  #pragma unroll
  for(int n=0;n<16;++n){ag[n]=0.f;am[n]=0.f;}
  const float4* wgp=(const float4*)(Wg + f*128);
  const float4* wmp=(const float4*)(Wm + f*128);
  for(int k=0;k<32;++k){
    float4 wg=wgp[k], wm=wmp[k];
    #pragma unroll
    for(int n=0;n<16;++n){
      float4 hv=*(const float4*)&h_lds[n][k*4];
      ag[n]+=dot4(wg,hv); am[n]+=dot4(wm,hv);
    }
  }
  #pragma unroll
  for(int n=0;n<16;++n){
    xt_g[(n0+n)*128+f]=ag[n];
    xt_m[(n0+n)*128+f]=am[n];
  }
  const float csg=att_sg[f], cdg=att_dg[f], csm=att_sm[f], cdm=att_dm[f];
  const int lane=f&63, wid=f>>6;
  for(int n=0;n<16;++n){
    float vx=ag[n]*csg, vy=ag[n]*cdg, vz=am[n]*csm, vw=am[n]*cdm;
    #pragma unroll
    for(int m=32;m;m>>=1){
      vx+=__shfl_xor(vx,m); vy+=__shfl_xor(vy,m);
      vz+=__shfl_xor(vz,m); vw+=__shfl_xor(vw,m);
    }
    if(lane==0){ wred[wid][0]=vx; wred[wid][1]=vy; wred[wid][2]=vz; wred[wid][3]=vw; }
    __syncthreads();
    if(f==0){
      float gg=gsc_g[n0+n], gm=gsc_m[n0+n];
      ssg[n0+n]=wred[0][0]+wred[1][0]+gg;
      sdg[n0+n]=wred[0][1]+wred[1][1]-gg;
      ssm[n0+n]=wred[0][2]+wred[1][2]+gm;
      sdm[n0+n]=wred[0][3]+wred[1][3]-gm;
    }
    __syncthreads();
  }
}

// ---------------- per-layer dual GAT aggregate + gated h update (in-place) ----------------
__global__ __launch_bounds__(256) void gat_aggregate(
    const int* __restrict__ rowptr, const int* __restrict__ csr_src,
    const float* __restrict__ xt_g, const float* __restrict__ xt_m,
    const float* __restrict__ ssg, const float* __restrict__ sdg,
    const float* __restrict__ ssm, const float* __restrict__ sdm,
    const float* __restrict__ bias_g, const float* __restrict__ bias_m,
    float* __restrict__ h)
{
  const int lane=threadIdx.x&63;
  const int n=blockIdx.x*4+(threadIdx.x>>6);
  const int s0=rowptr[n], s1=rowptr[n+1];
  const int deg=s1-s0;
  const float bg=sdg[n], bm=sdm[n];
  float mg=-1e30f, mm=-1e30f;
  for(int i=lane;i<deg;i+=64){
    int s=csr_src[s0+i];
    mg=fmaxf(mg,leaky(ssg[s]+bg));
    mm=fmaxf(mm,leaky(ssm[s]+bm));
  }
  mg=wave_rmax(mg); mm=wave_rmax(mm);
  float dg=0.f,dm=0.f,ag0=0.f,ag1=0.f,am0=0.f,am1=0.f;
  for(int c=0;c<deg;c+=64){
    int i=c+lane; int s=0; float eg=0.f,em=0.f;
    if(i<deg){
      s=csr_src[s0+i];
      eg=__expf(leaky(ssg[s]+bg)-mg);
      em=__expf(leaky(ssm[s]+bm)-mm);
      dg+=eg; dm+=em;
    }
    int cntc=min(64,deg-c);
    for(int j=0;j<cntc;++j){
      int ss=__shfl(s,j);
      float egj=__shfl(eg,j), emj=__shfl(em,j);
      const float* xg=xt_g+ss*128;
      const float* xm=xt_m+ss*128;
      ag0+=egj*xg[lane];    ag1+=egj*xg[64+lane];
      am0+=emj*xm[lane];    am1+=emj*xm[64+lane];
    }
  }
  dg=wave_rsum(dg); dm=wave_rsum(dm);
  float rg=rcpf(dg+1e-16f), rm=rcpf(dm+1e-16f);
  float og0=ag0*rg+bias_g[lane], og1=ag1*rg+bias_g[64+lane];
  float om0=am0*rm+bias_m[lane], om1=am1*rm+bias_m[64+lane];
  float tau0=sigm(og0), tau1=sigm(og1);
  float msg0=swishf(om0), msg1=swishf(om1);
  float h0=h[n*128+lane], h1=h[n*128+64+lane];
  h[n*128+lane]   =(1.0f-tau0)*h0+tau0*msg0;
  h[n*128+64+lane]=(1.0f-tau1)*h1+tau1*msg1;
}

// ---------------- decoder ----------------
__global__ __launch_bounds__(256) void decoder_kernel(
    const float* __restrict__ h, const float* __restrict__ u,
    const float* __restrict__ Wd, const float* __restrict__ bd,
    const float* __restrict__ w1, const float* __restrict__ b1,
    const float* __restrict__ w2, const float* __restrict__ b2,
    float* __restrict__ out)
{
  __shared__ float h_lds[8][128];
  __shared__ float h2[8][2][128];
  __shared__ float c1[8][8][38];
  __shared__ float w1s[256], w2s[224], b1s[8], b2s[2];
  const int tid=threadIdx.x;
  const int n0=blockIdx.x*8;
  for(int i=tid;i<8*128;i+=256) ((float*)h_lds)[i]=h[n0*128+i];
  w1s[tid]=w1[tid];
  if(tid<224) w2s[tid]=w2[tid];
  if(tid<8) b1s[tid]=b1[tid];
  if(tid<2) b2s[tid]=b2[tid];
  __syncthreads();
  {
    const float4* wp=(const float4*)(Wd + tid*128);
    float acc[8];
    #pragma unroll
    for(int n=0;n<8;++n)acc[n]=0.f;
    for(int k=0;k<32;++k){
      float4 w=wp[k];
      #pragma unroll
      for(int n=0;n<8;++n){ float4 hv=*(const float4*)&h_lds[n][k*4]; acc[n]+=dot4(w,hv); }
    }
    float bdv=bd[tid];
    int ch=tid>>7, p=tid&127;
    #pragma unroll
    for(int n=0;n<8;++n) h2[n][ch][p]=swishf(acc[n]+bdv);
  }
  __syncthreads();
  for(int idx=tid; idx<8*8*38; idx+=256){
    int n=idx/(8*38); int r=idx%(8*38); int oc=r/38, p=r%38;
    float acc=b1s[oc];
    const float* ww=&w1s[oc*32];
    #pragma unroll
    for(int ic=0;ic<2;++ic)
      #pragma unroll
      for(int k=0;k<16;++k) acc+=ww[ic*16+k]*h2[n][ic][3*p+k];
    c1[n][oc][p]=swishf(acc);
  }
  __syncthreads();
  for(int idx=tid; idx<8*2*25; idx+=256){
    int n=idx/50; int r=idx%50; int oc=r/25, p=r%25;
    float acc=b2s[oc];
    const float* ww=&w2s[oc*112];
    #pragma unroll
    for(int ic=0;ic<8;++ic)
      #pragma unroll
      for(int k=0;k<14;++k) acc+=ww[ic*14+k]*c1[n][ic][p+k];
    int col=oc*25+p;
    out[(n0+n)*50+col]=u[(n0+n)*50+col]+0.04f*(float)(p+1)*acc;
  }
}

extern "C" void kernel_launch(void* const* d_in, const int* in_sizes, int n_in,
                              void* d_out, int out_size, void* d_ws, size_t ws_size,
                              hipStream_t stream)
{
  const float* u          =(const float*)d_in[0];
  const float* pos        =(const float*)d_in[1];
  const int*   ei         =(const int*)d_in[2];
  const float* lem_inp_w  =(const float*)d_in[3];
  const float* lem_inp_b  =(const float*)d_in[4];
  const float* lem_hid_w  =(const float*)d_in[5];
  const float* lem_hid_b  =(const float*)d_in[6];
  const float* lem_z_w    =(const float*)d_in[7];
  const float* lem_z_b    =(const float*)d_in[8];
  const float* mlp1_w     =(const float*)d_in[9];
  const float* mlp1_b     =(const float*)d_in[10];
  const float* mlp2_w     =(const float*)d_in[11];
  const float* mlp2_b     =(const float*)d_in[12];
  const float* gnn_lin_w  =(const float*)d_in[13];
  const float* gnn_edge_w =(const float*)d_in[14];
  const float* gnn_att_src=(const float*)d_in[15];
  const float* gnn_att_dst=(const float*)d_in[16];
  const float* gnn_att_edge=(const float*)d_in[17];
  const float* gnn_bias   =(const float*)d_in[18];
  const float* gate_lin_w =(const float*)d_in[19];
  const float* gate_edge_w=(const float*)d_in[20];
  const float* gate_att_src=(const float*)d_in[21];
  const float* gate_att_dst=(const float*)d_in[22];
  const float* gate_att_edge=(const float*)d_in[23];
  const float* gate_bias  =(const float*)d_in[24];
  const float* dbl_w      =(const float*)d_in[25];
  const float* dbl_b      =(const float*)d_in[26];
  const float* conv1_w    =(const float*)d_in[27];
  const float* conv1_b    =(const float*)d_in[28];
  const float* conv2_w    =(const float*)d_in[29];
  const float* conv2_b    =(const float*)d_in[30];
  float* out=(float*)d_out;

  char* ws=(char*)d_ws;
  size_t off=0;
  auto alloc=[&](size_t bytes)->char*{ char* p=ws+off; off+=(bytes+255)&~(size_t)255; return p; };
  float* h    =(float*)alloc((size_t)N_NODES*128*4);
  float* xt_g =(float*)alloc((size_t)N_NODES*128*4);
  float* xt_m =(float*)alloc((size_t)N_NODES*128*4);
  float* ssg  =(float*)alloc(N_NODES*4);
  float* sdg  =(float*)alloc(N_NODES*4);
  float* ssm  =(float*)alloc(N_NODES*4);
  float* sdm  =(float*)alloc(N_NODES*4);
  float* gsc  =(float*)alloc((size_t)12*N_NODES*4);
  float* wearr=(float*)alloc(12*51*4);
  int* cnt    =(int*)alloc(N_NODES*4);
  int* rowptr =(int*)alloc((N_NODES+8)*4);
  int* cursor =(int*)alloc(N_NODES*4);
  int* csrsrc =(int*)alloc((size_t)N_EDGES*4);
  short* whb  =(short*)alloc(384*128*2);
  short* wzb  =(short*)alloc(128*128*2);
  short* w1b  =(short*)alloc(128*128*2);
  short* w2b  =(short*)alloc(128*128*2);

  const int* src=ei;
  const int* dst=ei+N_EDGES;

  hipMemsetAsync(cnt,0,N_NODES*4,stream);
  hist_kernel<<<N_EDGES/256,256,0,stream>>>(dst,cnt);
  scan_kernel<<<1,1024,0,stream>>>(cnt,rowptr,cursor);
  scatter_kernel<<<N_EDGES/256,256,0,stream>>>(src,dst,cursor,csrsrc);
  tobf16_kernel<<<(384*128+255)/256,256,0,stream>>>(lem_hid_w,whb,384*128);
  tobf16_kernel<<<(128*128+255)/256,256,0,stream>>>(lem_z_w,wzb,128*128);
  tobf16_kernel<<<(128*128+255)/256,256,0,stream>>>(mlp1_w,w1b,128*128);
  tobf16_kernel<<<(128*128+255)/256,256,0,stream>>>(mlp2_w,w2b,128*128);
  we_kernel<<<3,256,0,stream>>>(gate_edge_w,gnn_edge_w,gate_att_edge,gnn_att_edge,wearr);
  gsc_kernel<<<N_NODES/128,128,0,stream>>>(u,pos,wearr,gsc);
  lem_mfma_kernel<<<N_NODES/16,512,0,stream>>>(u,pos,lem_inp_w,lem_inp_b,whb,lem_hid_b,
                                               wzb,lem_z_b,w1b,mlp1_b,w2b,mlp2_b,h);
  for(int l=0;l<6;++l){
    gat_transform<<<N_NODES/16,128,0,stream>>>(h,
      gate_lin_w+(size_t)l*128*128, gnn_lin_w+(size_t)l*128*128,
      gate_att_src+l*128, gate_att_dst+l*128,
      gnn_att_src+l*128, gnn_att_dst+l*128,
      gsc+(size_t)(2*l)*N_NODES, gsc+(size_t)(2*l+1)*N_NODES,
      xt_g, xt_m, ssg, sdg, ssm, sdm);
    gat_aggregate<<<N_NODES/4,256,0,stream>>>(rowptr,csrsrc,xt_g,xt_m,ssg,sdg,ssm,sdm,
      gate_bias+l*128, gnn_bias+l*128, h);
  }
  decoder_kernel<<<N_NODES/8,256,0,stream>>>(h,u,dbl_w,dbl_b,conv1_w,conv1_b,conv2_w,conv2_b,out);
}

// Round 3
// 451.675 us; speedup vs baseline: 3.8215x; 1.4764x over previous
//
#include <hip/hip_runtime.h>

#define N_NODES 8192
#define N_EDGES 131072

using short8 = __attribute__((ext_vector_type(8))) short;
using f32x4  = __attribute__((ext_vector_type(4))) float;

__device__ __forceinline__ float rcpf(float x){ return __builtin_amdgcn_rcpf(x); }
__device__ __forceinline__ float sigm(float x){ return rcpf(1.0f+__expf(-x)); }
__device__ __forceinline__ float ftanh(float x){ float e=__expf(2.0f*x); return (e-1.0f)*rcpf(e+1.0f); }
__device__ __forceinline__ float swishf(float x){ return x*sigm(x); }
__device__ __forceinline__ float leaky(float x){ return x>=0.0f? x : 0.2f*x; }
__device__ __forceinline__ float dot4(float4 a, float4 b){ return a.x*b.x+a.y*b.y+a.z*b.z+a.w*b.w; }
__device__ __forceinline__ short f2bf(float x){
  unsigned u=__float_as_uint(x);
  unsigned r=(u + 0x7fffu + ((u>>16)&1u))>>16;
  return (short)r;
}

__device__ __forceinline__ float wave_rmax(float v){
  #pragma unroll
  for(int m=32;m;m>>=1) v=fmaxf(v,__shfl_xor(v,m));
  return v;
}
__device__ __forceinline__ float wave_rsum(float v){
  #pragma unroll
  for(int m=32;m;m>>=1) v+=__shfl_xor(v,m);
  return v;
}

// ---------------- CSR build ----------------
__global__ __launch_bounds__(256) void hist_kernel(const int* __restrict__ dst, int* __restrict__ cnt){
  int e=blockIdx.x*256+threadIdx.x;
  if(e<N_EDGES) atomicAdd(&cnt[dst[e]],1);
}

__global__ __launch_bounds__(1024) void scan_kernel(const int* __restrict__ cnt, int* __restrict__ rowptr, int* __restrict__ cursor){
  __shared__ int sums[1024];
  int t=threadIdx.x; int base=t*8;
  int local[8]; int s=0;
  #pragma unroll
  for(int i=0;i<8;++i){ local[i]=s; s+=cnt[base+i]; }
  sums[t]=s; __syncthreads();
  for(int off=1;off<1024;off<<=1){
    int v=(t>=off)?sums[t-off]:0;
    __syncthreads();
    sums[t]+=v;
    __syncthreads();
  }
  int offset=(t>0)?sums[t-1]:0;
  #pragma unroll
  for(int i=0;i<8;++i){ int v=offset+local[i]; rowptr[base+i]=v; cursor[base+i]=v; }
  if(t==1023) rowptr[N_NODES]=sums[1023];
}

__global__ __launch_bounds__(256) void scatter_kernel(const int* __restrict__ src, const int* __restrict__ dst,
                                                      int* __restrict__ cursor, int* __restrict__ csr_src){
  int e=blockIdx.x*256+threadIdx.x;
  if(e<N_EDGES){
    int slot=atomicAdd(&cursor[dst[e]],1);
    csr_src[slot]=src[e];
  }
}

// ---------------- fused fp32 -> bf16 weight prep ----------------
// [0,49152) lem_hid_w -> whb ; [49152,65536) lem_z_w -> wzb ; [65536,81920) mlp1_w -> w1b ;
// [81920,98304) mlp2_w -> w2b ; [98304,294912) gate/gnn lin (interleaved per layer) -> wlin16
__global__ __launch_bounds__(256) void prep_bf16_kernel(
    const float* __restrict__ lem_hid_w, const float* __restrict__ lem_z_w,
    const float* __restrict__ mlp1_w, const float* __restrict__ mlp2_w,
    const float* __restrict__ gate_lin_w, const float* __restrict__ gnn_lin_w,
    short* __restrict__ whb, short* __restrict__ wzb, short* __restrict__ w1b,
    short* __restrict__ w2b, short* __restrict__ wlin16)
{
  int i=blockIdx.x*256+threadIdx.x;
  if(i<49152){ whb[i]=f2bf(lem_hid_w[i]); return; }
  if(i<65536){ int k=i-49152; wzb[k]=f2bf(lem_z_w[k]); return; }
  if(i<81920){ int k=i-65536; w1b[k]=f2bf(mlp1_w[k]); return; }
  if(i<98304){ int k=i-81920; w2b[k]=f2bf(mlp2_w[k]); return; }
  int k=i-98304;                 // [6][2][16384]
  int l=k>>15, which=(k>>14)&1, r=k&16383;
  const float* s = which? gnn_lin_w + l*16384 + r : gate_lin_w + l*16384 + r;
  wlin16[k]=f2bf(*s);
}

// ---------------- edge-weight collapse ----------------
__global__ __launch_bounds__(256) void we_kernel(const float* __restrict__ gate_ew, const float* __restrict__ gnn_ew,
                                                 const float* __restrict__ gate_ae, const float* __restrict__ gnn_ae,
                                                 float* __restrict__ we){
  int idx=blockIdx.x*256+threadIdx.x;
  if(idx>=12*51) return;
  int g=idx/51, k=idx%51, l=g>>1;
  const float* ew = (g&1)? gnn_ew + l*128*51 : gate_ew + l*128*51;
  const float* ae = (g&1)? gnn_ae + l*128    : gate_ae + l*128;
  float s=0.f;
  for(int f=0;f<128;++f) s+=ew[f*51+k]*ae[f];
  we[idx]=s;
}

__global__ __launch_bounds__(128) void gsc_kernel(const float* __restrict__ u, const float* __restrict__ pos,
                                                  const float* __restrict__ we, float* __restrict__ gsc){
  int n=blockIdx.x*128+threadIdx.x;
  float uv[50];
  #pragma unroll
  for(int k=0;k<50;++k) uv[k]=u[n*50+k];
  float px=pos[n*2+1]*(1.0f/16.0f);
  for(int g=0;g<12;++g){
    const float* w=we+g*51;
    float s=w[50]*px;
    #pragma unroll
    for(int k=0;k<50;++k) s+=w[k]*uv[k];
    gsc[g*N_NODES+n]=s;
  }
}

// ---------------- LEM scan (MFMA) + output MLP, fused ----------------
__global__ __launch_bounds__(512,2) void lem_mfma_kernel(
    const float* __restrict__ u, const float* __restrict__ pos,
    const float* __restrict__ Wi, const float* __restrict__ bi,
    const short* __restrict__ whb, const float* __restrict__ bh,
    const short* __restrict__ wzb, const float* __restrict__ bz,
    const short* __restrict__ w1b, const float* __restrict__ b1,
    const short* __restrict__ w2b, const float* __restrict__ b2,
    float* __restrict__ hout)
{
  __shared__ float hh[16*385];
  __shared__ short y16[16*128];
  __shared__ short z16[16*128];
  __shared__ float u_s[16*50];
  __shared__ float px_s[16], pt_s[16];

  const int tid=threadIdx.x;
  const int lane=tid&63;
  const int w=tid>>6;
  const int n0=blockIdx.x*16;
  const int r16=lane&15, kq=lane>>4;

  for(int i=tid;i<16*50;i+=512) u_s[i]=u[n0*50+i];
  if(tid<16){ px_s[tid]=pos[(n0+tid)*2+1]*(1.0f/16.0f); pt_s[tid]=pos[(n0+tid)*2+0]*0.25f; }
  for(int i=tid;i<16*128;i+=512) y16[i]=0;

  const int f=tid&127;
  const int g=tid>>7;
  const float4 wi1=*(const float4*)(Wi+4*f);
  const float4 wi2=*(const float4*)(Wi+4*(128+f));
  const float4 wi3=*(const float4*)(Wi+4*(256+f));
  const float4 wi4=*(const float4*)(Wi+4*(384+f));
  const float bi1=bi[f], bi2=bi[128+f], bi3=bi[256+f], bi4=bi[384+f];
  const float bh1=bh[f], bh2=bh[128+f], bh3=bh[256+f], bzf=bz[f];

  short8 whf[3][4];
  #pragma unroll
  for(int t3=0;t3<3;++t3)
    #pragma unroll
    for(int kk=0;kk<4;++kk)
      whf[t3][kk]=*(const short8*)(whb + (w*48+t3*16+r16)*128 + kk*32 + kq*8);
  short8 wzf[4];
  #pragma unroll
  for(int kk=0;kk<4;++kk)
    wzf[kk]=*(const short8*)(wzb + (w*16+r16)*128 + kk*32 + kq*8);

  float yreg[4]={0.f,0.f,0.f,0.f}, zreg[4]={0.f,0.f,0.f,0.f};
  float msb[4], i4s[4];
  __syncthreads();

  for(int t=0;t<25;++t){
    // Phase A: hh = y @ Wh^T  (16x384)
    {
      f32x4 a0={0.f,0.f,0.f,0.f}, a1=a0, a2=a0;
      #pragma unroll
      for(int kk=0;kk<4;++kk){
        short8 ya=*(const short8*)&y16[r16*128 + ((kk*32+kq*8) ^ ((r16&7)<<3))];
        a0=__builtin_amdgcn_mfma_f32_16x16x32_bf16(ya,whf[0][kk],a0,0,0,0);
        a1=__builtin_amdgcn_mfma_f32_16x16x32_bf16(ya,whf[1][kk],a1,0,0,0);
        a2=__builtin_amdgcn_mfma_f32_16x16x32_bf16(ya,whf[2][kk],a2,0,0,0);
      }
      #pragma unroll
      for(int r=0;r<4;++r){
        int row=kq*4+r;
        hh[row*385 + w*48 +      r16]=a0[r];
        hh[row*385 + w*48 + 16 + r16]=a1[r];
        hh[row*385 + w*48 + 32 + r16]=a2[r];
      }
    }
    __syncthreads();
    // Phase B: elementwise z update
    #pragma unroll
    for(int j=0;j<4;++j){
      int n=4*g+j;
      float px=px_s[n], u0=u_s[n*50+t], u1=u_s[n*50+25+t], tsv=pt_s[n]+0.04f*(float)(t+1);
      float i1=bi1+wi1.x*px+wi1.y*u0+wi1.z*u1+wi1.w*tsv;
      float i2=bi2+wi2.x*px+wi2.y*u0+wi2.z*u1+wi2.w*tsv;
      float i3=bi3+wi3.x*px+wi3.y*u0+wi3.z*u1+wi3.w*tsv;
      float i4=bi4+wi4.x*px+wi4.y*u0+wi4.z*u1+wi4.w*tsv;
      float h1=hh[n*385+f], h2=hh[n*385+128+f], h3=hh[n*385+256+f];
      msb[j]=sigm(i1+h1+bh1);
      float ms=sigm(i2+h2+bh2);
      float zn=(1.0f-ms)*zreg[j]+ms*ftanh(i3+h3+bh3);
      zreg[j]=zn; i4s[j]=i4;
      z16[n*128 + (f ^ ((n&7)<<3))]=f2bf(zn);
    }
    __syncthreads();
    // Phase C: zw = z @ Wz^T -> hh cols 0..127
    {
      f32x4 a={0.f,0.f,0.f,0.f};
      #pragma unroll
      for(int kk=0;kk<4;++kk){
        short8 za=*(const short8*)&z16[r16*128 + ((kk*32+kq*8) ^ ((r16&7)<<3))];
        a=__builtin_amdgcn_mfma_f32_16x16x32_bf16(za,wzf[kk],a,0,0,0);
      }
      #pragma unroll
      for(int r=0;r<4;++r) hh[(kq*4+r)*385 + w*16 + r16]=a[r];
    }
    __syncthreads();
    // Phase D: y update
    #pragma unroll
    for(int j=0;j<4;++j){
      int n=4*g+j;
      float zw=hh[n*385+f];
      float yn=(1.0f-msb[j])*yreg[j]+msb[j]*ftanh(zw+bzf+i4s[j]);
      yreg[j]=yn;
      y16[n*128 + (f ^ ((n&7)<<3))]=f2bf(yn);
    }
    __syncthreads();
  }

  // MLP1: t1 = swish(y @ W1^T + b1) -> z16 (bf16, swizzled)
  {
    short8 wf[4];
    #pragma unroll
    for(int kk=0;kk<4;++kk)
      wf[kk]=*(const short8*)(w1b + (w*16+r16)*128 + kk*32 + kq*8);
    float b1v=b1[w*16+r16];
    f32x4 a={0.f,0.f,0.f,0.f};
    #pragma unroll
    for(int kk=0;kk<4;++kk){
      short8 ya=*(const short8*)&y16[r16*128 + ((kk*32+kq*8) ^ ((r16&7)<<3))];
      a=__builtin_amdgcn_mfma_f32_16x16x32_bf16(ya,wf[kk],a,0,0,0);
    }
    #pragma unroll
    for(int r=0;r<4;++r){
      int row=kq*4+r;
      float v=swishf(a[r]+b1v);
      z16[row*128 + ((w*16+r16) ^ ((row&7)<<3))]=f2bf(v);
    }
  }
  __syncthreads();
  // MLP2: h = swish(t1 @ W2^T + b2) -> global
  {
    short8 wf[4];
    #pragma unroll
    for(int kk=0;kk<4;++kk)
      wf[kk]=*(const short8*)(w2b + (w*16+r16)*128 + kk*32 + kq*8);
    float b2v=b2[w*16+r16];
    f32x4 a={0.f,0.f,0.f,0.f};
    #pragma unroll
    for(int kk=0;kk<4;++kk){
      short8 za=*(const short8*)&z16[r16*128 + ((kk*32+kq*8) ^ ((r16&7)<<3))];
      a=__builtin_amdgcn_mfma_f32_16x16x32_bf16(za,wf[kk],a,0,0,0);
    }
    #pragma unroll
    for(int r=0;r<4;++r){
      int row=kq*4+r;
      hout[(n0+row)*128 + w*16 + r16]=swishf(a[r]+b2v);
    }
  }
}

// ---------------- GAT transform via MFMA: xt16 = bf16(h @ [Wg|Wm]^T), ss2/sd2 fp32 ----------------
// 256 threads = 4 waves, 32 nodes/block. wave: rt=w&1 row-tile (16 nodes), cg=w>>1 (0 gate, 1 gnn).
__global__ __launch_bounds__(256) void gat_transform_mfma(
    const float* __restrict__ h,
    const short* __restrict__ wl,     // [2][128][128] bf16 for this layer
    const float* __restrict__ a_sg, const float* __restrict__ a_dg,
    const float* __restrict__ a_sm, const float* __restrict__ a_dm,
    const float* __restrict__ gsc_g, const float* __restrict__ gsc_m,
    short* __restrict__ xt16, float* __restrict__ ss2, float* __restrict__ sd2)
{
  __shared__ short h16[32*128];
  __shared__ short xts[32*256];
  const int tid=threadIdx.x, lane=tid&63, w=tid>>6;
  const int rt=w&1, cg=w>>1;
  const int r16=lane&15, kq=lane>>4;
  const int n0=blockIdx.x*32;

  // stage h -> bf16 swizzled (16 floats per thread)
  {
    const float4* hp=(const float4*)(h + (size_t)n0*128) + tid*4;
    int row=tid>>3, e0=(tid&7)*16;
    #pragma unroll
    for(int c=0;c<2;++c){
      float4 v0=hp[2*c], v1=hp[2*c+1];
      short8 s;
      s[0]=f2bf(v0.x); s[1]=f2bf(v0.y); s[2]=f2bf(v0.z); s[3]=f2bf(v0.w);
      s[4]=f2bf(v1.x); s[5]=f2bf(v1.y); s[6]=f2bf(v1.z); s[7]=f2bf(v1.w);
      *(short8*)&h16[row*128 + ((e0+8*c) ^ ((row&7)<<3))]=s;
    }
  }
  __syncthreads();
  short8 afr[4];
  {
    int row=rt*16+r16;
    #pragma unroll
    for(int kk=0;kk<4;++kk)
      afr[kk]=*(const short8*)&h16[row*128 + ((kk*32+kq*8) ^ ((row&7)<<3))];
  }
  const short* wb = wl + cg*16384;
  const float* as_ = cg? a_sm : a_sg;
  const float* ad_ = cg? a_dm : a_dg;
  float ssp[4]={0,0,0,0}, sdp[4]={0,0,0,0};
  #pragma unroll
  for(int ct=0;ct<8;++ct){
    int c0=ct*16;
    f32x4 acc={0.f,0.f,0.f,0.f};
    #pragma unroll
    for(int kk=0;kk<4;++kk){
      short8 b=*(const short8*)(wb + (c0+r16)*128 + kk*32 + kq*8);
      acc=__builtin_amdgcn_mfma_f32_16x16x32_bf16(afr[kk],b,acc,0,0,0);
    }
    float av=as_[c0+r16], dv=ad_[c0+r16];
    #pragma unroll
    for(int r=0;r<4;++r){
      ssp[r]+=acc[r]*av; sdp[r]+=acc[r]*dv;
      xts[(rt*16+kq*4+r)*256 + cg*128 + c0 + r16]=f2bf(acc[r]);
    }
  }
  // reduce over r16 (cols) within 16-lane groups
  #pragma unroll
  for(int m=1;m<16;m<<=1){
    #pragma unroll
    for(int r=0;r<4;++r){
      ssp[r]+=__shfl_xor(ssp[r],m);
      sdp[r]+=__shfl_xor(sdp[r],m);
    }
  }
  if(r16==0){
    #pragma unroll
    for(int r=0;r<4;++r){
      int n=n0+rt*16+kq*4+r;
      float gv = (cg? gsc_m : gsc_g)[n];
      ss2[2*n+cg]=ssp[r]+gv;
      sd2[2*n+cg]=sdp[r]-gv;
    }
  }
  __syncthreads();
  const short8* sp=(const short8*)xts;
  short8* dp=(short8*)(xt16 + (size_t)n0*256);
  for(int i=tid;i<32*256/8;i+=256) dp[i]=sp[i];
}

// ---------------- dual GAT aggregate + gated h update; bf16 xt rows ----------------
// one wave per node; lane<32: gate feats 4l..4l+3; lane>=32: gnn feats 4(l-32)..
__global__ __launch_bounds__(256) void gat_aggregate2(
    const int* __restrict__ rowptr, const int* __restrict__ csr_src,
    const short* __restrict__ xt16,
    const float* __restrict__ ss2, const float* __restrict__ sd2,
    const float* __restrict__ bias_g, const float* __restrict__ bias_m,
    float* __restrict__ h)
{
  __shared__ float4 stg[4][64];
  const int lane=threadIdx.x&63, w=threadIdx.x>>6;
  const int n=blockIdx.x*4+w;
  const int s0=rowptr[n], deg=rowptr[n+1]-s0;
  const float2 sdv=*(const float2*)(sd2+2*n);
  const float bg=sdv.x, bm=sdv.y;

  float mg=-1e30f, mm=-1e30f;
  int sc=0; float lgc=0.f, lmc=0.f;
  for(int c=0;c<deg;c+=64){
    int i=c+lane;
    if(i<deg){
      int s=csr_src[s0+i];
      float2 ssv=*(const float2*)(ss2+2*s);
      float lg=leaky(ssv.x+bg), lm=leaky(ssv.y+bm);
      if(c==0){sc=s; lgc=lg; lmc=lm;}
      mg=fmaxf(mg,lg); mm=fmaxf(mm,lm);
    }
  }
  mg=wave_rmax(mg); mm=wave_rmax(mm);

  float dg=0.f, dm=0.f;
  float acc0=0.f,acc1=0.f,acc2=0.f,acc3=0.f;
  for(int c=0;c<deg;c+=64){
    int i=c+lane;
    int s=sc; float lg=lgc, lm=lmc;
    if(c>0 && i<deg){
      s=csr_src[s0+i];
      float2 ssv=*(const float2*)(ss2+2*s);
      lg=leaky(ssv.x+bg); lm=leaky(ssv.y+bm);
    }
    float eg=0.f, em=0.f;
    if(i<deg){ eg=__expf(lg-mg); em=__expf(lm-mm); dg+=eg; dm+=em; }
    float4 st; st.x=__int_as_float(s); st.y=eg; st.z=em; st.w=0.f;
    stg[w][lane]=st;
    __threadfence_block();
    int cntc=min(64,deg-c);
    for(int j=0;j<cntc;++j){
      float4 e=stg[w][j];
      int sj=__float_as_int(e.x);
      float wgt = lane<32 ? e.y : e.z;
      const unsigned* xp=(const unsigned*)(xt16 + (size_t)sj*256 + 4*lane);
      unsigned p0=xp[0], p1=xp[1];
      acc0 += wgt*__uint_as_float(p0<<16);
      acc1 += wgt*__uint_as_float(p0&0xffff0000u);
      acc2 += wgt*__uint_as_float(p1<<16);
      acc3 += wgt*__uint_as_float(p1&0xffff0000u);
    }
  }
  dg=wave_rsum(dg); dm=wave_rsum(dm);
  float rr = lane<32? rcpf(dg+1e-16f) : rcpf(dm+1e-16f);
  const float* bp = lane<32 ? bias_g + 4*lane : bias_m + 4*(lane-32);
  float4 bv=*(const float4*)bp;
  float o0=acc0*rr+bv.x, o1=acc1*rr+bv.y, o2=acc2*rr+bv.z, o3=acc3*rr+bv.w;
  // sigm for gate lanes; swish = o*sigm for gnn lanes (branchless)
  float s0_=sigm(o0), s1_=sigm(o1), s2_=sigm(o2), s3_=sigm(o3);
  float v0 = lane<32? s0_ : o0*s0_;
  float v1 = lane<32? s1_ : o1*s1_;
  float v2 = lane<32? s2_ : o2*s2_;
  float v3 = lane<32? s3_ : o3*s3_;
  float m0=__shfl_xor(v0,32), m1=__shfl_xor(v1,32), m2=__shfl_xor(v2,32), m3=__shfl_xor(v3,32);
  if(lane<32){
    float4 hv=*(const float4*)(h + (size_t)n*128 + 4*lane);
    hv.x=(1.0f-v0)*hv.x+v0*m0;
    hv.y=(1.0f-v1)*hv.y+v1*m1;
    hv.z=(1.0f-v2)*hv.z+v2*m2;
    hv.w=(1.0f-v3)*hv.w+v3*m3;
    *(float4*)(h + (size_t)n*128 + 4*lane)=hv;
  }
}

// ---------------- decoder ----------------
__global__ __launch_bounds__(256) void decoder_kernel(
    const float* __restrict__ h, const float* __restrict__ u,
    const float* __restrict__ Wd, const float* __restrict__ bd,
    const float* __restrict__ w1, const float* __restrict__ b1,
    const float* __restrict__ w2, const float* __restrict__ b2,
    float* __restrict__ out)
{
  __shared__ float h_lds[8][128];
  __shared__ float h2[8][2][128];
  __shared__ float c1[8][8][38];
  __shared__ float w1s[256], w2s[224], b1s[8], b2s[2];
  const int tid=threadIdx.x;
  const int n0=blockIdx.x*8;
  for(int i=tid;i<8*128;i+=256) ((float*)h_lds)[i]=h[n0*128+i];
  w1s[tid]=w1[tid];
  if(tid<224) w2s[tid]=w2[tid];
  if(tid<8) b1s[tid]=b1[tid];
  if(tid<2) b2s[tid]=b2[tid];
  __syncthreads();
  {
    const float4* wp=(const float4*)(Wd + tid*128);
    float acc[8];
    #pragma unroll
    for(int n=0;n<8;++n)acc[n]=0.f;
    for(int k=0;k<32;++k){
      float4 w=wp[k];
      #pragma unroll
      for(int n=0;n<8;++n){ float4 hv=*(const float4*)&h_lds[n][k*4]; acc[n]+=dot4(w,hv); }
    }
    float bdv=bd[tid];
    int ch=tid>>7, p=tid&127;
    #pragma unroll
    for(int n=0;n<8;++n) h2[n][ch][p]=swishf(acc[n]+bdv);
  }
  __syncthreads();
  for(int idx=tid; idx<8*8*38; idx+=256){
    int n=idx/(8*38); int r=idx%(8*38); int oc=r/38, p=r%38;
    float acc=b1s[oc];
    const float* ww=&w1s[oc*32];
    #pragma unroll
    for(int ic=0;ic<2;++ic)
      #pragma unroll
      for(int k=0;k<16;++k) acc+=ww[ic*16+k]*h2[n][ic][3*p+k];
    c1[n][oc][p]=swishf(acc);
  }
  __syncthreads();
  for(int idx=tid; idx<8*2*25; idx+=256){
    int n=idx/50; int r=idx%50; int oc=r/25, p=r%25;
    float acc=b2s[oc];
    const float* ww=&w2s[oc*112];
    #pragma unroll
    for(int ic=0;ic<8;++ic)
      #pragma unroll
      for(int k=0;k<14;++k) acc+=ww[ic*14+k]*c1[n][ic][p+k];
    int col=oc*25+p;
    out[(n0+n)*50+col]=u[(n0+n)*50+col]+0.04f*(float)(p+1)*acc;
  }
}

extern "C" void kernel_launch(void* const* d_in, const int* in_sizes, int n_in,
                              void* d_out, int out_size, void* d_ws, size_t ws_size,
                              hipStream_t stream)
{
  const float* u          =(const float*)d_in[0];
  const float* pos        =(const float*)d_in[1];
  const int*   ei         =(const int*)d_in[2];
  const float* lem_inp_w  =(const float*)d_in[3];
  const float* lem_inp_b  =(const float*)d_in[4];
  const float* lem_hid_w  =(const float*)d_in[5];
  const float* lem_hid_b  =(const float*)d_in[6];
  const float* lem_z_w    =(const float*)d_in[7];
  const float* lem_z_b    =(const float*)d_in[8];
  const float* mlp1_w     =(const float*)d_in[9];
  const float* mlp1_b     =(const float*)d_in[10];
  const float* mlp2_w     =(const float*)d_in[11];
  const float* mlp2_b     =(const float*)d_in[12];
  const float* gnn_lin_w  =(const float*)d_in[13];
  const float* gnn_edge_w =(const float*)d_in[14];
  const float* gnn_att_src=(const float*)d_in[15];
  const float* gnn_att_dst=(const float*)d_in[16];
  const float* gnn_att_edge=(const float*)d_in[17];
  const float* gnn_bias   =(const float*)d_in[18];
  const float* gate_lin_w =(const float*)d_in[19];
  const float* gate_edge_w=(const float*)d_in[20];
  const float* gate_att_src=(const float*)d_in[21];
  const float* gate_att_dst=(const float*)d_in[22];
  const float* gate_att_edge=(const float*)d_in[23];
  const float* gate_bias  =(const float*)d_in[24];
  const float* dbl_w      =(const float*)d_in[25];
  const float* dbl_b      =(const float*)d_in[26];
  const float* conv1_w    =(const float*)d_in[27];
  const float* conv1_b    =(const float*)d_in[28];
  const float* conv2_w    =(const float*)d_in[29];
  const float* conv2_b    =(const float*)d_in[30];
  float* out=(float*)d_out;

  char* ws=(char*)d_ws;
  size_t off=0;
  auto alloc=[&](size_t bytes)->char*{ char* p=ws+off; off+=(bytes+255)&~(size_t)255; return p; };
  float* h    =(float*)alloc((size_t)N_NODES*128*4);
  short* xt16 =(short*)alloc((size_t)N_NODES*256*2);
  float* ss2  =(float*)alloc((size_t)N_NODES*2*4);
  float* sd2  =(float*)alloc((size_t)N_NODES*2*4);
  float* gsc  =(float*)alloc((size_t)12*N_NODES*4);
  float* wearr=(float*)alloc(12*51*4);
  int* cnt    =(int*)alloc(N_NODES*4);
  int* rowptr =(int*)alloc((N_NODES+8)*4);
  int* cursor =(int*)alloc(N_NODES*4);
  int* csrsrc =(int*)alloc((size_t)N_EDGES*4);
  short* whb  =(short*)alloc(384*128*2);
  short* wzb  =(short*)alloc(128*128*2);
  short* w1b  =(short*)alloc(128*128*2);
  short* w2b  =(short*)alloc(128*128*2);
  short* wlin16=(short*)alloc((size_t)6*2*128*128*2);

  const int* src=ei;
  const int* dst=ei+N_EDGES;

  hipMemsetAsync(cnt,0,N_NODES*4,stream);
  hist_kernel<<<N_EDGES/256,256,0,stream>>>(dst,cnt);
  scan_kernel<<<1,1024,0,stream>>>(cnt,rowptr,cursor);
  scatter_kernel<<<N_EDGES/256,256,0,stream>>>(src,dst,cursor,csrsrc);
  prep_bf16_kernel<<<(294912+255)/256,256,0,stream>>>(lem_hid_w,lem_z_w,mlp1_w,mlp2_w,
                                                      gate_lin_w,gnn_lin_w,
                                                      whb,wzb,w1b,w2b,wlin16);
  we_kernel<<<3,256,0,stream>>>(gate_edge_w,gnn_edge_w,gate_att_edge,gnn_att_edge,wearr);
  gsc_kernel<<<N_NODES/128,128,0,stream>>>(u,pos,wearr,gsc);
  lem_mfma_kernel<<<N_NODES/16,512,0,stream>>>(u,pos,lem_inp_w,lem_inp_b,whb,lem_hid_b,
                                               wzb,lem_z_b,w1b,mlp1_b,w2b,mlp2_b,h);
  for(int l=0;l<6;++l){
    gat_transform_mfma<<<N_NODES/32,256,0,stream>>>(h,
      wlin16+(size_t)l*2*16384,
      gate_att_src+l*128, gate_att_dst+l*128,
      gnn_att_src+l*128, gnn_att_dst+l*128,
      gsc+(size_t)(2*l)*N_NODES, gsc+(size_t)(2*l+1)*N_NODES,
      xt16, ss2, sd2);
    gat_aggregate2<<<N_NODES/4,256,0,stream>>>(rowptr,csrsrc,xt16,ss2,sd2,
      gate_bias+l*128, gnn_bias+l*128, h);
  }
  decoder_kernel<<<N_NODES/8,256,0,stream>>>(h,u,dbl_w,dbl_b,conv1_w,conv1_b,conv2_w,conv2_b,out);
}

// Round 4
// 423.955 us; speedup vs baseline: 4.0714x; 1.0654x over previous
//
#include <hip/hip_runtime.h>

#define N_NODES 8192
#define N_EDGES 131072

using short8 = __attribute__((ext_vector_type(8))) short;
using f32x4  = __attribute__((ext_vector_type(4))) float;

__device__ __forceinline__ float rcpf(float x){ return __builtin_amdgcn_rcpf(x); }
__device__ __forceinline__ float sigm(float x){ return rcpf(1.0f+__expf(-x)); }
__device__ __forceinline__ float ftanh(float x){ float e=__expf(2.0f*x); return (e-1.0f)*rcpf(e+1.0f); }
__device__ __forceinline__ float swishf(float x){ return x*sigm(x); }
__device__ __forceinline__ float leaky(float x){ return x>=0.0f? x : 0.2f*x; }
__device__ __forceinline__ float dot4(float4 a, float4 b){ return a.x*b.x+a.y*b.y+a.z*b.z+a.w*b.w; }
__device__ __forceinline__ short f2bf(float x){
  unsigned u=__float_as_uint(x);
  unsigned r=(u + 0x7fffu + ((u>>16)&1u))>>16;
  return (short)r;
}
__device__ __forceinline__ int pack2bf(float a, float b){
  return (int)(((unsigned)(unsigned short)f2bf(a)) | (((unsigned)(unsigned short)f2bf(b))<<16));
}

__device__ __forceinline__ float wave_rmax(float v){
  #pragma unroll
  for(int m=32;m;m>>=1) v=fmaxf(v,__shfl_xor(v,m));
  return v;
}
__device__ __forceinline__ float wave_rsum(float v){
  #pragma unroll
  for(int m=32;m;m>>=1) v+=__shfl_xor(v,m);
  return v;
}

// ---------------- CSR build ----------------
__global__ __launch_bounds__(256) void hist_kernel(const int* __restrict__ dst, int* __restrict__ cnt){
  int e=blockIdx.x*256+threadIdx.x;
  if(e<N_EDGES) atomicAdd(&cnt[dst[e]],1);
}

__global__ __launch_bounds__(1024) void scan_kernel(const int* __restrict__ cnt, int* __restrict__ rowptr, int* __restrict__ cursor){
  __shared__ int sums[1024];
  int t=threadIdx.x; int base=t*8;
  int local[8]; int s=0;
  #pragma unroll
  for(int i=0;i<8;++i){ local[i]=s; s+=cnt[base+i]; }
  sums[t]=s; __syncthreads();
  for(int off=1;off<1024;off<<=1){
    int v=(t>=off)?sums[t-off]:0;
    __syncthreads();
    sums[t]+=v;
    __syncthreads();
  }
  int offset=(t>0)?sums[t-1]:0;
  #pragma unroll
  for(int i=0;i<8;++i){ int v=offset+local[i]; rowptr[base+i]=v; cursor[base+i]=v; }
  if(t==1023) rowptr[N_NODES]=sums[1023];
}

__global__ __launch_bounds__(256) void scatter_kernel(const int* __restrict__ src, const int* __restrict__ dst,
                                                      int* __restrict__ cursor, int* __restrict__ csr_src){
  int e=blockIdx.x*256+threadIdx.x;
  if(e<N_EDGES){
    int slot=atomicAdd(&cursor[dst[e]],1);
    csr_src[slot]=src[e];
  }
}

// ---------------- fused fp32 -> bf16 weight prep ----------------
__global__ __launch_bounds__(256) void prep_bf16_kernel(
    const float* __restrict__ lem_hid_w, const float* __restrict__ lem_z_w,
    const float* __restrict__ mlp1_w, const float* __restrict__ mlp2_w,
    const float* __restrict__ gate_lin_w, const float* __restrict__ gnn_lin_w,
    short* __restrict__ whb, short* __restrict__ wzb, short* __restrict__ w1b,
    short* __restrict__ w2b, short* __restrict__ wlin16)
{
  int i=blockIdx.x*256+threadIdx.x;
  if(i<49152){ whb[i]=f2bf(lem_hid_w[i]); return; }
  if(i<65536){ int k=i-49152; wzb[k]=f2bf(lem_z_w[k]); return; }
  if(i<81920){ int k=i-65536; w1b[k]=f2bf(mlp1_w[k]); return; }
  if(i<98304){ int k=i-81920; w2b[k]=f2bf(mlp2_w[k]); return; }
  int k=i-98304;                 // [6][2][16384]
  int l=k>>15, which=(k>>14)&1, r=k&16383;
  const float* s = which? gnn_lin_w + l*16384 + r : gate_lin_w + l*16384 + r;
  wlin16[k]=f2bf(*s);
}

// ---------------- edge-weight collapse ----------------
__global__ __launch_bounds__(256) void we_kernel(const float* __restrict__ gate_ew, const float* __restrict__ gnn_ew,
                                                 const float* __restrict__ gate_ae, const float* __restrict__ gnn_ae,
                                                 float* __restrict__ we){
  int idx=blockIdx.x*256+threadIdx.x;
  if(idx>=12*51) return;
  int g=idx/51, k=idx%51, l=g>>1;
  const float* ew = (g&1)? gnn_ew + l*128*51 : gate_ew + l*128*51;
  const float* ae = (g&1)? gnn_ae + l*128    : gate_ae + l*128;
  float s=0.f;
  for(int f=0;f<128;++f) s+=ew[f*51+k]*ae[f];
  we[idx]=s;
}

__global__ __launch_bounds__(128) void gsc_kernel(const float* __restrict__ u, const float* __restrict__ pos,
                                                  const float* __restrict__ we, float* __restrict__ gsc){
  int n=blockIdx.x*128+threadIdx.x;
  float uv[50];
  #pragma unroll
  for(int k=0;k<50;++k) uv[k]=u[n*50+k];
  float px=pos[n*2+1]*(1.0f/16.0f);
  for(int g=0;g<12;++g){
    const float* w=we+g*51;
    float s=w[50]*px;
    #pragma unroll
    for(int k=0;k<50;++k) s+=w[k]*uv[k];
    gsc[g*N_NODES+n]=s;
  }
}

// ---------------- LEM scan (MFMA, transposed orientation) + output MLP ----------------
// 512 threads = 8 waves, 16 nodes/block. Output layout D: col=node(lane&15),
// row=feature w*16 + (lane>>4)*4 + r  -> elementwise updates are in-lane.
// 2 barriers per step.
__global__ __launch_bounds__(512,2) void lem_mfma2_kernel(
    const float* __restrict__ u, const float* __restrict__ pos,
    const float* __restrict__ Wi, const float* __restrict__ bi,
    const short* __restrict__ whb, const float* __restrict__ bh,
    const short* __restrict__ wzb, const float* __restrict__ bz,
    const short* __restrict__ w1b, const float* __restrict__ b1,
    const short* __restrict__ w2b, const float* __restrict__ b2,
    float* __restrict__ hout)
{
  __shared__ short y16[16*128];
  __shared__ short z16[16*128];
  __shared__ float u_s[16*50];
  __shared__ float hstg[16*132];

  const int tid=threadIdx.x, lane=tid&63, w=tid>>6;
  const int node=lane&15, q=lane>>4;
  const int n7=node&7;
  const int n0=blockIdx.x*16;

  for(int i=tid;i<16*50;i+=512) u_s[i]=u[n0*50+i];
  for(int i=tid;i<16*64;i+=512) ((int*)y16)[i]=0;

  const float px = pos[(n0+node)*2+1]*(1.0f/16.0f);
  const float pt = pos[(n0+node)*2+0]*0.25f;

  // per-lane input coefficients: features fr = w*16+q*4+r, gates 0..3
  float cbase[4][4], cslope[4][4], ca[4][4], cb[4][4];
  #pragma unroll
  for(int gg=0; gg<4; ++gg){
    #pragma unroll
    for(int r=0;r<4;++r){
      int fr = w*16+q*4+r;
      int row = gg*128+fr;
      float4 wi = *(const float4*)(Wi+4*row);
      float bb = bi[row] + ((gg<3)? bh[row] : bz[fr]);
      cbase[gg][r] = bb + wi.x*px + wi.w*pt;
      cslope[gg][r]= wi.w*0.04f;
      ca[gg][r]=wi.y; cb[gg][r]=wi.z;
    }
  }

  // weight A-fragments (A lane row = lane&15 -> Wh row gg*128 + w*16 + node)
  short8 whf[3][4];
  #pragma unroll
  for(int gg=0;gg<3;++gg)
    #pragma unroll
    for(int kk=0;kk<4;++kk)
      whf[gg][kk]=*(const short8*)(whb + (gg*128 + w*16 + node)*128 + kk*32 + q*8);
  short8 wzf[4];
  #pragma unroll
  for(int kk=0;kk<4;++kk)
    wzf[kk]=*(const short8*)(wzb + (w*16 + node)*128 + kk*32 + q*8);

  float yreg[4]={0.f,0.f,0.f,0.f}, zreg[4]={0.f,0.f,0.f,0.f};
  float msb[4], i4s[4];
  const int wrslot = (w*16+q*4) ^ (n7<<3);   // packed b64 write slot (shorts)
  __syncthreads();

  for(int t=0;t<25;++t){
    // Phase A: S = Wh . y^T  (B-frag: features of node from y16)
    f32x4 h1a={0.f,0.f,0.f,0.f}, h2a=h1a, h3a=h1a;
    #pragma unroll
    for(int kk=0;kk<4;++kk){
      short8 yb=*(const short8*)&y16[node*128 + ((kk*32 + q*8) ^ (n7<<3))];
      h1a=__builtin_amdgcn_mfma_f32_16x16x32_bf16(whf[0][kk],yb,h1a,0,0,0);
      h2a=__builtin_amdgcn_mfma_f32_16x16x32_bf16(whf[1][kk],yb,h2a,0,0,0);
      h3a=__builtin_amdgcn_mfma_f32_16x16x32_bf16(whf[2][kk],yb,h3a,0,0,0);
    }
    const float u0=u_s[node*50+t], u1=u_s[node*50+25+t];
    const float tf=(float)(t+1);
    #pragma unroll
    for(int r=0;r<4;++r){
      float i1=cbase[0][r]+cslope[0][r]*tf+ca[0][r]*u0+cb[0][r]*u1;
      float i2=cbase[1][r]+cslope[1][r]*tf+ca[1][r]*u0+cb[1][r]*u1;
      float i3=cbase[2][r]+cslope[2][r]*tf+ca[2][r]*u0+cb[2][r]*u1;
      i4s[r]  =cbase[3][r]+cslope[3][r]*tf+ca[3][r]*u0+cb[3][r]*u1;
      msb[r]=sigm(i1+h1a[r]);
      float ms=sigm(i2+h2a[r]);
      zreg[r]=(1.0f-ms)*zreg[r]+ms*ftanh(i3+h3a[r]);
    }
    { int2 zz; zz.x=pack2bf(zreg[0],zreg[1]); zz.y=pack2bf(zreg[2],zreg[3]);
      *(int2*)&z16[node*128 + wrslot]=zz; }
    __syncthreads();
    // Phase C: ZW = Wz . z^T
    f32x4 zw={0.f,0.f,0.f,0.f};
    #pragma unroll
    for(int kk=0;kk<4;++kk){
      short8 zb=*(const short8*)&z16[node*128 + ((kk*32 + q*8) ^ (n7<<3))];
      zw=__builtin_amdgcn_mfma_f32_16x16x32_bf16(wzf[kk],zb,zw,0,0,0);
    }
    #pragma unroll
    for(int r=0;r<4;++r)
      yreg[r]=(1.0f-msb[r])*yreg[r]+msb[r]*ftanh(zw[r]+i4s[r]);
    { int2 yy; yy.x=pack2bf(yreg[0],yreg[1]); yy.y=pack2bf(yreg[2],yreg[3]);
      *(int2*)&y16[node*128 + wrslot]=yy; }
    __syncthreads();
  }

  // MLP1: t1 = swish(W1 . y^T + b1) -> z16
  {
    short8 w1f[4];
    #pragma unroll
    for(int kk=0;kk<4;++kk)
      w1f[kk]=*(const short8*)(w1b + (w*16 + node)*128 + kk*32 + q*8);
    float4 b1v=*(const float4*)(b1 + w*16 + q*4);
    f32x4 a={0.f,0.f,0.f,0.f};
    #pragma unroll
    for(int kk=0;kk<4;++kk){
      short8 yb=*(const short8*)&y16[node*128 + ((kk*32 + q*8) ^ (n7<<3))];
      a=__builtin_amdgcn_mfma_f32_16x16x32_bf16(w1f[kk],yb,a,0,0,0);
    }
    float t0=swishf(a[0]+b1v.x), t1=swishf(a[1]+b1v.y);
    float t2=swishf(a[2]+b1v.z), t3=swishf(a[3]+b1v.w);
    int2 zz; zz.x=pack2bf(t0,t1); zz.y=pack2bf(t2,t3);
    *(int2*)&z16[node*128 + wrslot]=zz;
  }
  __syncthreads();
  // MLP2: h = swish(W2 . t1^T + b2) -> hstg -> hout
  {
    short8 w2f[4];
    #pragma unroll
    for(int kk=0;kk<4;++kk)
      w2f[kk]=*(const short8*)(w2b + (w*16 + node)*128 + kk*32 + q*8);
    float4 b2v=*(const float4*)(b2 + w*16 + q*4);
    f32x4 a={0.f,0.f,0.f,0.f};
    #pragma unroll
    for(int kk=0;kk<4;++kk){
      short8 zb=*(const short8*)&z16[node*128 + ((kk*32 + q*8) ^ (n7<<3))];
      a=__builtin_amdgcn_mfma_f32_16x16x32_bf16(w2f[kk],zb,a,0,0,0);
    }
    hstg[node*132 + w*16+q*4+0]=swishf(a[0]+b2v.x);
    hstg[node*132 + w*16+q*4+1]=swishf(a[1]+b2v.y);
    hstg[node*132 + w*16+q*4+2]=swishf(a[2]+b2v.z);
    hstg[node*132 + w*16+q*4+3]=swishf(a[3]+b2v.w);
  }
  __syncthreads();
  for(int i=tid;i<16*128;i+=512){
    int nn=i>>7, ff=i&127;
    hout[(n0+nn)*128+ff]=hstg[nn*132+ff];
  }
}

// ---------------- GAT transform via MFMA ----------------
__global__ __launch_bounds__(256) void gat_transform_mfma(
    const float* __restrict__ h,
    const short* __restrict__ wl,     // [2][128][128] bf16 for this layer
    const float* __restrict__ a_sg, const float* __restrict__ a_dg,
    const float* __restrict__ a_sm, const float* __restrict__ a_dm,
    const float* __restrict__ gsc_g, const float* __restrict__ gsc_m,
    short* __restrict__ xt16, float* __restrict__ ss2, float* __restrict__ sd2)
{
  __shared__ short h16[32*128];
  __shared__ short xts[32*256];
  const int tid=threadIdx.x, lane=tid&63, w=tid>>6;
  const int rt=w&1, cg=w>>1;
  const int r16=lane&15, kq=lane>>4;
  const int n0=blockIdx.x*32;

  {
    const float4* hp=(const float4*)(h + (size_t)n0*128) + tid*4;
    int row=tid>>3, e0=(tid&7)*16;
    #pragma unroll
    for(int c=0;c<2;++c){
      float4 v0=hp[2*c], v1=hp[2*c+1];
      short8 s;
      s[0]=f2bf(v0.x); s[1]=f2bf(v0.y); s[2]=f2bf(v0.z); s[3]=f2bf(v0.w);
      s[4]=f2bf(v1.x); s[5]=f2bf(v1.y); s[6]=f2bf(v1.z); s[7]=f2bf(v1.w);
      *(short8*)&h16[row*128 + ((e0+8*c) ^ ((row&7)<<3))]=s;
    }
  }
  __syncthreads();
  short8 afr[4];
  {
    int row=rt*16+r16;
    #pragma unroll
    for(int kk=0;kk<4;++kk)
      afr[kk]=*(const short8*)&h16[row*128 + ((kk*32+kq*8) ^ ((row&7)<<3))];
  }
  const short* wb = wl + cg*16384;
  const float* as_ = cg? a_sm : a_sg;
  const float* ad_ = cg? a_dm : a_dg;
  float ssp[4]={0,0,0,0}, sdp[4]={0,0,0,0};
  #pragma unroll
  for(int ct=0;ct<8;++ct){
    int c0=ct*16;
    f32x4 acc={0.f,0.f,0.f,0.f};
    #pragma unroll
    for(int kk=0;kk<4;++kk){
      short8 b=*(const short8*)(wb + (c0+r16)*128 + kk*32 + kq*8);
      acc=__builtin_amdgcn_mfma_f32_16x16x32_bf16(afr[kk],b,acc,0,0,0);
    }
    float av=as_[c0+r16], dv=ad_[c0+r16];
    #pragma unroll
    for(int r=0;r<4;++r){
      ssp[r]+=acc[r]*av; sdp[r]+=acc[r]*dv;
      xts[(rt*16+kq*4+r)*256 + cg*128 + c0 + r16]=f2bf(acc[r]);
    }
  }
  #pragma unroll
  for(int m=1;m<16;m<<=1){
    #pragma unroll
    for(int r=0;r<4;++r){
      ssp[r]+=__shfl_xor(ssp[r],m);
      sdp[r]+=__shfl_xor(sdp[r],m);
    }
  }
  if(r16==0){
    #pragma unroll
    for(int r=0;r<4;++r){
      int n=n0+rt*16+kq*4+r;
      float gv = (cg? gsc_m : gsc_g)[n];
      ss2[2*n+cg]=ssp[r]+gv;
      sd2[2*n+cg]=sdp[r]-gv;
    }
  }
  __syncthreads();
  const short8* sp=(const short8*)xts;
  short8* dp=(short8*)(xt16 + (size_t)n0*256);
  for(int i=tid;i<32*256/8;i+=256) dp[i]=sp[i];
}

// ---------------- dual GAT aggregate + gated h update ----------------
__global__ __launch_bounds__(256) void gat_aggregate2(
    const int* __restrict__ rowptr, const int* __restrict__ csr_src,
    const short* __restrict__ xt16,
    const float* __restrict__ ss2, const float* __restrict__ sd2,
    const float* __restrict__ bias_g, const float* __restrict__ bias_m,
    float* __restrict__ h)
{
  __shared__ float4 stg[4][64];
  const int lane=threadIdx.x&63, w=threadIdx.x>>6;
  const int n=blockIdx.x*4+w;
  const int s0=rowptr[n], deg=rowptr[n+1]-s0;
  const float2 sdv=*(const float2*)(sd2+2*n);
  const float bg=sdv.x, bm=sdv.y;

  float mg=-1e30f, mm=-1e30f;
  int sc=0; float lgc=0.f, lmc=0.f;
  for(int c=0;c<deg;c+=64){
    int i=c+lane;
    if(i<deg){
      int s=csr_src[s0+i];
      float2 ssv=*(const float2*)(ss2+2*s);
      float lg=leaky(ssv.x+bg), lm=leaky(ssv.y+bm);
      if(c==0){sc=s; lgc=lg; lmc=lm;}
      mg=fmaxf(mg,lg); mm=fmaxf(mm,lm);
    }
  }
  mg=wave_rmax(mg); mm=wave_rmax(mm);

  float dg=0.f, dm=0.f;
  float acc0=0.f,acc1=0.f,acc2=0.f,acc3=0.f;
  for(int c=0;c<deg;c+=64){
    int i=c+lane;
    int s=sc; float lg=lgc, lm=lmc;
    if(c>0 && i<deg){
      s=csr_src[s0+i];
      float2 ssv=*(const float2*)(ss2+2*s);
      lg=leaky(ssv.x+bg); lm=leaky(ssv.y+bm);
    }
    float eg=0.f, em=0.f;
    if(i<deg){ eg=__expf(lg-mg); em=__expf(lm-mm); dg+=eg; dm+=em; }
    float4 st; st.x=__int_as_float(s); st.y=eg; st.z=em; st.w=0.f;
    stg[w][lane]=st;
    __threadfence_block();
    int cntc=min(64,deg-c);
    for(int j=0;j<cntc;++j){
      float4 e=stg[w][j];
      int sj=__float_as_int(e.x);
      float wgt = lane<32 ? e.y : e.z;
      const unsigned* xp=(const unsigned*)(xt16 + (size_t)sj*256 + 4*lane);
      unsigned p0=xp[0], p1=xp[1];
      acc0 += wgt*__uint_as_float(p0<<16);
      acc1 += wgt*__uint_as_float(p0&0xffff0000u);
      acc2 += wgt*__uint_as_float(p1<<16);
      acc3 += wgt*__uint_as_float(p1&0xffff0000u);
    }
  }
  dg=wave_rsum(dg); dm=wave_rsum(dm);
  float rr = lane<32? rcpf(dg+1e-16f) : rcpf(dm+1e-16f);
  const float* bp = lane<32 ? bias_g + 4*lane : bias_m + 4*(lane-32);
  float4 bv=*(const float4*)bp;
  float o0=acc0*rr+bv.x, o1=acc1*rr+bv.y, o2=acc2*rr+bv.z, o3=acc3*rr+bv.w;
  float s0_=sigm(o0), s1_=sigm(o1), s2_=sigm(o2), s3_=sigm(o3);
  float v0 = lane<32? s0_ : o0*s0_;
  float v1 = lane<32? s1_ : o1*s1_;
  float v2 = lane<32? s2_ : o2*s2_;
  float v3 = lane<32? s3_ : o3*s3_;
  float m0=__shfl_xor(v0,32), m1=__shfl_xor(v1,32), m2=__shfl_xor(v2,32), m3=__shfl_xor(v3,32);
  if(lane<32){
    float4 hv=*(const float4*)(h + (size_t)n*128 + 4*lane);
    hv.x=(1.0f-v0)*hv.x+v0*m0;
    hv.y=(1.0f-v1)*hv.y+v1*m1;
    hv.z=(1.0f-v2)*hv.z+v2*m2;
    hv.w=(1.0f-v3)*hv.w+v3*m3;
    *(float4*)(h + (size_t)n*128 + 4*lane)=hv;
  }
}

// ---------------- decoder ----------------
__global__ __launch_bounds__(256) void decoder_kernel(
    const float* __restrict__ h, const float* __restrict__ u,
    const float* __restrict__ Wd, const float* __restrict__ bd,
    const float* __restrict__ w1, const float* __restrict__ b1,
    const float* __restrict__ w2, const float* __restrict__ b2,
    float* __restrict__ out)
{
  __shared__ float h_lds[8][128];
  __shared__ float h2[8][2][128];
  __shared__ float c1[8][8][38];
  __shared__ float w1s[256], w2s[224], b1s[8], b2s[2];
  const int tid=threadIdx.x;
  const int n0=blockIdx.x*8;
  for(int i=tid;i<8*128;i+=256) ((float*)h_lds)[i]=h[n0*128+i];
  w1s[tid]=w1[tid];
  if(tid<224) w2s[tid]=w2[tid];
  if(tid<8) b1s[tid]=b1[tid];
  if(tid<2) b2s[tid]=b2[tid];
  __syncthreads();
  {
    const float4* wp=(const float4*)(Wd + tid*128);
    float acc[8];
    #pragma unroll
    for(int n=0;n<8;++n)acc[n]=0.f;
    for(int k=0;k<32;++k){
      float4 w=wp[k];
      #pragma unroll
      for(int n=0;n<8;++n){ float4 hv=*(const float4*)&h_lds[n][k*4]; acc[n]+=dot4(w,hv); }
    }
    float bdv=bd[tid];
    int ch=tid>>7, p=tid&127;
    #pragma unroll
    for(int n=0;n<8;++n) h2[n][ch][p]=swishf(acc[n]+bdv);
  }
  __syncthreads();
  for(int idx=tid; idx<8*8*38; idx+=256){
    int n=idx/(8*38); int r=idx%(8*38); int oc=r/38, p=r%38;
    float acc=b1s[oc];
    const float* ww=&w1s[oc*32];
    #pragma unroll
    for(int ic=0;ic<2;++ic)
      #pragma unroll
      for(int k=0;k<16;++k) acc+=ww[ic*16+k]*h2[n][ic][3*p+k];
    c1[n][oc][p]=swishf(acc);
  }
  __syncthreads();
  for(int idx=tid; idx<8*2*25; idx+=256){
    int n=idx/50; int r=idx%50; int oc=r/25, p=r%25;
    float acc=b2s[oc];
    const float* ww=&w2s[oc*112];
    #pragma unroll
    for(int ic=0;ic<8;++ic)
      #pragma unroll
      for(int k=0;k<14;++k) acc+=ww[ic*14+k]*c1[n][ic][p+k];
    int col=oc*25+p;
    out[(n0+n)*50+col]=u[(n0+n)*50+col]+0.04f*(float)(p+1)*acc;
  }
}

extern "C" void kernel_launch(void* const* d_in, const int* in_sizes, int n_in,
                              void* d_out, int out_size, void* d_ws, size_t ws_size,
                              hipStream_t stream)
{
  const float* u          =(const float*)d_in[0];
  const float* pos        =(const float*)d_in[1];
  const int*   ei         =(const int*)d_in[2];
  const float* lem_inp_w  =(const float*)d_in[3];
  const float* lem_inp_b  =(const float*)d_in[4];
  const float* lem_hid_w  =(const float*)d_in[5];
  const float* lem_hid_b  =(const float*)d_in[6];
  const float* lem_z_w    =(const float*)d_in[7];
  const float* lem_z_b    =(const float*)d_in[8];
  const float* mlp1_w     =(const float*)d_in[9];
  const float* mlp1_b     =(const float*)d_in[10];
  const float* mlp2_w     =(const float*)d_in[11];
  const float* mlp2_b     =(const float*)d_in[12];
  const float* gnn_lin_w  =(const float*)d_in[13];
  const float* gnn_edge_w =(const float*)d_in[14];
  const float* gnn_att_src=(const float*)d_in[15];
  const float* gnn_att_dst=(const float*)d_in[16];
  const float* gnn_att_edge=(const float*)d_in[17];
  const float* gnn_bias   =(const float*)d_in[18];
  const float* gate_lin_w =(const float*)d_in[19];
  const float* gate_edge_w=(const float*)d_in[20];
  const float* gate_att_src=(const float*)d_in[21];
  const float* gate_att_dst=(const float*)d_in[22];
  const float* gate_att_edge=(const float*)d_in[23];
  const float* gate_bias  =(const float*)d_in[24];
  const float* dbl_w      =(const float*)d_in[25];
  const float* dbl_b      =(const float*)d_in[26];
  const float* conv1_w    =(const float*)d_in[27];
  const float* conv1_b    =(const float*)d_in[28];
  const float* conv2_w    =(const float*)d_in[29];
  const float* conv2_b    =(const float*)d_in[30];
  float* out=(float*)d_out;

  char* ws=(char*)d_ws;
  size_t off=0;
  auto alloc=[&](size_t bytes)->char*{ char* p=ws+off; off+=(bytes+255)&~(size_t)255; return p; };
  float* h    =(float*)alloc((size_t)N_NODES*128*4);
  short* xt16 =(short*)alloc((size_t)N_NODES*256*2);
  float* ss2  =(float*)alloc((size_t)N_NODES*2*4);
  float* sd2  =(float*)alloc((size_t)N_NODES*2*4);
  float* gsc  =(float*)alloc((size_t)12*N_NODES*4);
  float* wearr=(float*)alloc(12*51*4);
  int* cnt    =(int*)alloc(N_NODES*4);
  int* rowptr =(int*)alloc((N_NODES+8)*4);
  int* cursor =(int*)alloc(N_NODES*4);
  int* csrsrc =(int*)alloc((size_t)N_EDGES*4);
  short* whb  =(short*)alloc(384*128*2);
  short* wzb  =(short*)alloc(128*128*2);
  short* w1b  =(short*)alloc(128*128*2);
  short* w2b  =(short*)alloc(128*128*2);
  short* wlin16=(short*)alloc((size_t)6*2*128*128*2);

  const int* src=ei;
  const int* dst=ei+N_EDGES;

  hipMemsetAsync(cnt,0,N_NODES*4,stream);
  hist_kernel<<<N_EDGES/256,256,0,stream>>>(dst,cnt);
  scan_kernel<<<1,1024,0,stream>>>(cnt,rowptr,cursor);
  scatter_kernel<<<N_EDGES/256,256,0,stream>>>(src,dst,cursor,csrsrc);
  prep_bf16_kernel<<<(294912+255)/256,256,0,stream>>>(lem_hid_w,lem_z_w,mlp1_w,mlp2_w,
                                                      gate_lin_w,gnn_lin_w,
                                                      whb,wzb,w1b,w2b,wlin16);
  we_kernel<<<3,256,0,stream>>>(gate_edge_w,gnn_edge_w,gate_att_edge,gnn_att_edge,wearr);
  gsc_kernel<<<N_NODES/128,128,0,stream>>>(u,pos,wearr,gsc);
  lem_mfma2_kernel<<<N_NODES/16,512,0,stream>>>(u,pos,lem_inp_w,lem_inp_b,whb,lem_hid_b,
                                                wzb,lem_z_b,w1b,mlp1_b,w2b,mlp2_b,h);
  for(int l=0;l<6;++l){
    gat_transform_mfma<<<N_NODES/32,256,0,stream>>>(h,
      wlin16+(size_t)l*2*16384,
      gate_att_src+l*128, gate_att_dst+l*128,
      gnn_att_src+l*128, gnn_att_dst+l*128,
      gsc+(size_t)(2*l)*N_NODES, gsc+(size_t)(2*l+1)*N_NODES,
      xt16, ss2, sd2);
    gat_aggregate2<<<N_NODES/4,256,0,stream>>>(rowptr,csrsrc,xt16,ss2,sd2,
      gate_bias+l*128, gnn_bias+l*128, h);
  }
  decoder_kernel<<<N_NODES/8,256,0,stream>>>(h,u,dbl_w,dbl_b,conv1_w,conv1_b,conv2_w,conv2_b,out);
}

// Round 5
// 376.078 us; speedup vs baseline: 4.5897x; 1.1273x over previous
//
#include <hip/hip_runtime.h>

#define N_NODES 8192
#define N_EDGES 131072

using short8 = __attribute__((ext_vector_type(8))) short;
using f32x4  = __attribute__((ext_vector_type(4))) float;

__device__ __forceinline__ float rcpf(float x){ return __builtin_amdgcn_rcpf(x); }
__device__ __forceinline__ float sigm(float x){ return rcpf(1.0f+__expf(-x)); }
__device__ __forceinline__ float ftanh(float x){ float e=__expf(2.0f*x); return (e-1.0f)*rcpf(e+1.0f); }
__device__ __forceinline__ float swishf(float x){ return x*sigm(x); }
__device__ __forceinline__ float leaky(float x){ return x>=0.0f? x : 0.2f*x; }
__device__ __forceinline__ float dot4(float4 a, float4 b){ return a.x*b.x+a.y*b.y+a.z*b.z+a.w*b.w; }
__device__ __forceinline__ short f2bf(float x){
  unsigned u=__float_as_uint(x);
  unsigned r=(u + 0x7fffu + ((u>>16)&1u))>>16;
  return (short)r;
}
__device__ __forceinline__ int pack2bf(float a, float b){
  return (int)(((unsigned)(unsigned short)f2bf(a)) | (((unsigned)(unsigned short)f2bf(b))<<16));
}

__device__ __forceinline__ float wave_rmax(float v){
  #pragma unroll
  for(int m=32;m;m>>=1) v=fmaxf(v,__shfl_xor(v,m));
  return v;
}
__device__ __forceinline__ float wave_rsum(float v){
  #pragma unroll
  for(int m=32;m;m>>=1) v+=__shfl_xor(v,m);
  return v;
}

// ---------------- CSR build ----------------
__global__ __launch_bounds__(256) void hist_kernel(const int* __restrict__ dst, int* __restrict__ cnt){
  int e=blockIdx.x*256+threadIdx.x;
  if(e<N_EDGES) atomicAdd(&cnt[dst[e]],1);
}

__global__ __launch_bounds__(1024) void scan_kernel(const int* __restrict__ cnt, int* __restrict__ rowptr, int* __restrict__ cursor){
  __shared__ int sums[1024];
  int t=threadIdx.x; int base=t*8;
  int local[8]; int s=0;
  #pragma unroll
  for(int i=0;i<8;++i){ local[i]=s; s+=cnt[base+i]; }
  sums[t]=s; __syncthreads();
  for(int off=1;off<1024;off<<=1){
    int v=(t>=off)?sums[t-off]:0;
    __syncthreads();
    sums[t]+=v;
    __syncthreads();
  }
  int offset=(t>0)?sums[t-1]:0;
  #pragma unroll
  for(int i=0;i<8;++i){ int v=offset+local[i]; rowptr[base+i]=v; cursor[base+i]=v; }
  if(t==1023) rowptr[N_NODES]=sums[1023];
}

__global__ __launch_bounds__(256) void scatter_kernel(const int* __restrict__ src, const int* __restrict__ dst,
                                                      int* __restrict__ cursor, int* __restrict__ csr_src){
  int e=blockIdx.x*256+threadIdx.x;
  if(e<N_EDGES){
    int slot=atomicAdd(&cursor[dst[e]],1);
    csr_src[slot]=src[e];
  }
}

// ---------------- fused fp32 -> bf16 weight prep ----------------
__global__ __launch_bounds__(256) void prep_bf16_kernel(
    const float* __restrict__ lem_hid_w, const float* __restrict__ lem_z_w,
    const float* __restrict__ mlp1_w, const float* __restrict__ mlp2_w,
    const float* __restrict__ gate_lin_w, const float* __restrict__ gnn_lin_w,
    short* __restrict__ whb, short* __restrict__ wzb, short* __restrict__ w1b,
    short* __restrict__ w2b, short* __restrict__ wlin16)
{
  int i=blockIdx.x*256+threadIdx.x;
  if(i<49152){ whb[i]=f2bf(lem_hid_w[i]); return; }
  if(i<65536){ int k=i-49152; wzb[k]=f2bf(lem_z_w[k]); return; }
  if(i<81920){ int k=i-65536; w1b[k]=f2bf(mlp1_w[k]); return; }
  if(i<98304){ int k=i-81920; w2b[k]=f2bf(mlp2_w[k]); return; }
  int k=i-98304;                 // [6][2][16384]
  int l=k>>15, which=(k>>14)&1, r=k&16383;
  const float* s = which? gnn_lin_w + l*16384 + r : gate_lin_w + l*16384 + r;
  wlin16[k]=f2bf(*s);
}

// ---------------- edge-weight collapse ----------------
__global__ __launch_bounds__(256) void we_kernel(const float* __restrict__ gate_ew, const float* __restrict__ gnn_ew,
                                                 const float* __restrict__ gate_ae, const float* __restrict__ gnn_ae,
                                                 float* __restrict__ we){
  int idx=blockIdx.x*256+threadIdx.x;
  if(idx>=12*51) return;
  int g=idx/51, k=idx%51, l=g>>1;
  const float* ew = (g&1)? gnn_ew + l*128*51 : gate_ew + l*128*51;
  const float* ae = (g&1)? gnn_ae + l*128    : gate_ae + l*128;
  float s=0.f;
  for(int f=0;f<128;++f) s+=ew[f*51+k]*ae[f];
  we[idx]=s;
}

__global__ __launch_bounds__(128) void gsc_kernel(const float* __restrict__ u, const float* __restrict__ pos,
                                                  const float* __restrict__ we, float* __restrict__ gsc){
  int n=blockIdx.x*128+threadIdx.x;
  float uv[50];
  #pragma unroll
  for(int k=0;k<50;++k) uv[k]=u[n*50+k];
  float px=pos[n*2+1]*(1.0f/16.0f);
  for(int g=0;g<12;++g){
    const float* w=we+g*51;
    float s=w[50]*px;
    #pragma unroll
    for(int k=0;k<50;++k) s+=w[k]*uv[k];
    gsc[g*N_NODES+n]=s;
  }
}

// ---------------- shared device pieces ----------------
// GAT transform for a block's 16 nodes. h16 = bf16 swizzled [16][128].
// 8 waves: cg=w&1 selects gate/gnn, ch=w>>1 selects 2 col-tiles. Contains 2 syncthreads.
__device__ __forceinline__ void transform_phase(
    int tid, int n0,
    const short* __restrict__ h16, short* __restrict__ xts,
    float* __restrict__ ssred, float* __restrict__ sdred,
    const short* __restrict__ wl,
    const float* __restrict__ a_sg, const float* __restrict__ a_dg,
    const float* __restrict__ a_sm, const float* __restrict__ a_dm,
    const float* __restrict__ gsc_g, const float* __restrict__ gsc_m,
    short* __restrict__ xt_out, float* __restrict__ ss_out, float* __restrict__ sd_out)
{
  const int lane=tid&63, w=tid>>6;
  const int cg=w&1, ch=w>>1;
  const int r16=lane&15, kq=lane>>4;
  __syncthreads();
  short8 afr[4];
  #pragma unroll
  for(int kk=0;kk<4;++kk)
    afr[kk]=*(const short8*)&h16[r16*128 + ((kk*32+kq*8) ^ ((r16&7)<<3))];
  const short* wb = wl + cg*16384;
  const float* as_ = cg? a_sm : a_sg;
  const float* ad_ = cg? a_dm : a_dg;
  float ssp[4]={0,0,0,0}, sdp[4]={0,0,0,0};
  #pragma unroll
  for(int ci=0;ci<2;++ci){
    int c0=(ch*2+ci)*16;
    f32x4 acc={0.f,0.f,0.f,0.f};
    #pragma unroll
    for(int kk=0;kk<4;++kk){
      short8 b=*(const short8*)(wb + (c0+r16)*128 + kk*32 + kq*8);
      acc=__builtin_amdgcn_mfma_f32_16x16x32_bf16(afr[kk],b,acc,0,0,0);
    }
    float av=as_[c0+r16], dv=ad_[c0+r16];
    #pragma unroll
    for(int r=0;r<4;++r){
      ssp[r]+=acc[r]*av; sdp[r]+=acc[r]*dv;
      xts[(kq*4+r)*256 + cg*128 + c0 + r16]=f2bf(acc[r]);
    }
  }
  #pragma unroll
  for(int m=1;m<16;m<<=1){
    #pragma unroll
    for(int r=0;r<4;++r){ ssp[r]+=__shfl_xor(ssp[r],m); sdp[r]+=__shfl_xor(sdp[r],m); }
  }
  if(r16==0){
    #pragma unroll
    for(int r=0;r<4;++r){ ssred[w*16+kq*4+r]=ssp[r]; sdred[w*16+kq*4+r]=sdp[r]; }
  }
  __syncthreads();
  if(tid<32){
    int node=tid&15, cg2=tid>>4;
    float sv=0.f, dv=0.f;
    #pragma unroll
    for(int c2=0;c2<4;++c2){ sv+=ssred[(c2*2+cg2)*16+node]; dv+=sdred[(c2*2+cg2)*16+node]; }
    float gv=(cg2? gsc_m:gsc_g)[n0+node];
    ss_out[2*(n0+node)+cg2]=sv+gv;
    sd_out[2*(n0+node)+cg2]=dv-gv;
  }
  // copy staged xt rows to global (one short8 per thread)
  {
    const short8* sp=(const short8*)xts;
    short8* dp=(short8*)(xt_out + (size_t)n0*256);
    dp[tid]=sp[tid];
  }
}

// Dual-GAT softmax aggregate for one node by one wave; returns blended h (valid lane<32).
__device__ __forceinline__ float4 aggregate_node(
    int n, int lane,
    const int* __restrict__ rowptr, const int* __restrict__ csr_src,
    const short* __restrict__ xt_in, const float* __restrict__ ss_in, const float* __restrict__ sd_in,
    const float* __restrict__ bias_g, const float* __restrict__ bias_m,
    const float* __restrict__ h)
{
  const int s0=rowptr[n], deg=rowptr[n+1]-s0;
  const float2 sdv=*(const float2*)(sd_in+2*n);
  const float bg=sdv.x, bm=sdv.y;
  float mg=-1e30f, mm=-1e30f;
  for(int c=0;c<deg;c+=64){
    int i=c+lane;
    if(i<deg){
      int s=csr_src[s0+i];
      float2 ssv=*(const float2*)(ss_in+2*s);
      mg=fmaxf(mg,leaky(ssv.x+bg)); mm=fmaxf(mm,leaky(ssv.y+bm));
    }
  }
  mg=wave_rmax(mg); mm=wave_rmax(mm);
  float dg=0.f,dm=0.f, acc0=0.f,acc1=0.f,acc2=0.f,acc3=0.f;
  for(int c=0;c<deg;c+=64){
    int i=c+lane, s=0; float eg=0.f, em=0.f;
    if(i<deg){
      s=csr_src[s0+i];
      float2 ssv=*(const float2*)(ss_in+2*s);
      eg=__expf(leaky(ssv.x+bg)-mg); em=__expf(leaky(ssv.y+bm)-mm);
      dg+=eg; dm+=em;
    }
    int cntc=min(64,deg-c);
    for(int cb=0;cb<cntc;cb+=8){
      int sj[8]; float wj[8];
      #pragma unroll
      for(int jj=0;jj<8;++jj){
        int idx=cb+jj;
        int sv=__shfl(s,idx);
        float wg=__shfl(eg,idx), wm=__shfl(em,idx);
        sj[jj]=sv;
        wj[jj]= lane<32? wg : wm;
      }
      uint2 rows[8];
      #pragma unroll
      for(int jj=0;jj<8;++jj)
        rows[jj]=*(const uint2*)(xt_in + (size_t)sj[jj]*256 + 4*lane);
      #pragma unroll
      for(int jj=0;jj<8;++jj){
        float wv=wj[jj];
        unsigned p0=rows[jj].x, p1=rows[jj].y;
        acc0+=wv*__uint_as_float(p0<<16);
        acc1+=wv*__uint_as_float(p0&0xffff0000u);
        acc2+=wv*__uint_as_float(p1<<16);
        acc3+=wv*__uint_as_float(p1&0xffff0000u);
      }
    }
  }
  dg=wave_rsum(dg); dm=wave_rsum(dm);
  float rr = lane<32? rcpf(dg+1e-16f) : rcpf(dm+1e-16f);
  const float* bp = lane<32? bias_g+4*lane : bias_m+4*(lane-32);
  float4 bv=*(const float4*)bp;
  float o0=acc0*rr+bv.x, o1=acc1*rr+bv.y, o2=acc2*rr+bv.z, o3=acc3*rr+bv.w;
  float s0_=sigm(o0), s1_=sigm(o1), s2_=sigm(o2), s3_=sigm(o3);
  float v0=lane<32? s0_:o0*s0_;
  float v1=lane<32? s1_:o1*s1_;
  float v2=lane<32? s2_:o2*s2_;
  float v3=lane<32? s3_:o3*s3_;
  float m0=__shfl_xor(v0,32), m1=__shfl_xor(v1,32), m2=__shfl_xor(v2,32), m3=__shfl_xor(v3,32);
  float4 r;
  if(lane<32){
    float4 hv=*(const float4*)(h + (size_t)n*128 + 4*lane);
    r.x=(1.0f-v0)*hv.x+v0*m0;
    r.y=(1.0f-v1)*hv.y+v1*m1;
    r.z=(1.0f-v2)*hv.z+v2*m2;
    r.w=(1.0f-v3)*hv.w+v3*m3;
  } else { r.x=r.y=r.z=r.w=0.f; }
  return r;
}

// ---------------- LEM scan (MFMA) + MLP + GAT transform layer 0 ----------------
__global__ __launch_bounds__(512,2) void lem_t0_kernel(
    const float* __restrict__ u, const float* __restrict__ pos,
    const float* __restrict__ Wi, const float* __restrict__ bi,
    const short* __restrict__ whb, const float* __restrict__ bh,
    const short* __restrict__ wzb, const float* __restrict__ bz,
    const short* __restrict__ w1b, const float* __restrict__ b1,
    const short* __restrict__ w2b, const float* __restrict__ b2,
    float* __restrict__ hout,
    const short* __restrict__ wl,
    const float* __restrict__ a_sg, const float* __restrict__ a_dg,
    const float* __restrict__ a_sm, const float* __restrict__ a_dm,
    const float* __restrict__ gsc_g, const float* __restrict__ gsc_m,
    short* __restrict__ xt_out, float* __restrict__ ss_out, float* __restrict__ sd_out)
{
  __shared__ short y16[16*128];
  __shared__ short z16[16*128];
  __shared__ float u_s[16*50];
  __shared__ float hstg[16*132];
  __shared__ short h16[16*128];
  __shared__ short xts[16*256];
  __shared__ float ssred[128], sdred[128];

  const int tid=threadIdx.x, lane=tid&63, w=tid>>6;
  const int node=lane&15, q=lane>>4;
  const int n7=node&7;
  const int n0=blockIdx.x*16;

  for(int i=tid;i<16*50;i+=512) u_s[i]=u[n0*50+i];
  for(int i=tid;i<16*64;i+=512) ((int*)y16)[i]=0;

  const float px = pos[(n0+node)*2+1]*(1.0f/16.0f);
  const float pt = pos[(n0+node)*2+0]*0.25f;

  float cbase[4][4], cslope[4][4], ca[4][4], cb[4][4];
  #pragma unroll
  for(int gg=0; gg<4; ++gg){
    #pragma unroll
    for(int r=0;r<4;++r){
      int fr = w*16+q*4+r;
      int row = gg*128+fr;
      float4 wi = *(const float4*)(Wi+4*row);
      float bb = bi[row] + ((gg<3)? bh[row] : bz[fr]);
      cbase[gg][r] = bb + wi.x*px + wi.w*pt;
      cslope[gg][r]= wi.w*0.04f;
      ca[gg][r]=wi.y; cb[gg][r]=wi.z;
    }
  }

  short8 whf[3][4];
  #pragma unroll
  for(int gg=0;gg<3;++gg)
    #pragma unroll
    for(int kk=0;kk<4;++kk)
      whf[gg][kk]=*(const short8*)(whb + (gg*128 + w*16 + node)*128 + kk*32 + q*8);
  short8 wzf[4];
  #pragma unroll
  for(int kk=0;kk<4;++kk)
    wzf[kk]=*(const short8*)(wzb + (w*16 + node)*128 + kk*32 + q*8);

  float yreg[4]={0.f,0.f,0.f,0.f}, zreg[4]={0.f,0.f,0.f,0.f};
  float msb[4], i4s[4];
  const int wrslot = (w*16+q*4) ^ (n7<<3);
  __syncthreads();

  for(int t=0;t<25;++t){
    f32x4 h1a={0.f,0.f,0.f,0.f}, h2a=h1a, h3a=h1a;
    #pragma unroll
    for(int kk=0;kk<4;++kk){
      short8 yb=*(const short8*)&y16[node*128 + ((kk*32 + q*8) ^ (n7<<3))];
      h1a=__builtin_amdgcn_mfma_f32_16x16x32_bf16(whf[0][kk],yb,h1a,0,0,0);
      h2a=__builtin_amdgcn_mfma_f32_16x16x32_bf16(whf[1][kk],yb,h2a,0,0,0);
      h3a=__builtin_amdgcn_mfma_f32_16x16x32_bf16(whf[2][kk],yb,h3a,0,0,0);
    }
    const float u0=u_s[node*50+t], u1=u_s[node*50+25+t];
    const float tf=(float)(t+1);
    #pragma unroll
    for(int r=0;r<4;++r){
      float i1=cbase[0][r]+cslope[0][r]*tf+ca[0][r]*u0+cb[0][r]*u1;
      float i2=cbase[1][r]+cslope[1][r]*tf+ca[1][r]*u0+cb[1][r]*u1;
      float i3=cbase[2][r]+cslope[2][r]*tf+ca[2][r]*u0+cb[2][r]*u1;
      i4s[r]  =cbase[3][r]+cslope[3][r]*tf+ca[3][r]*u0+cb[3][r]*u1;
      msb[r]=sigm(i1+h1a[r]);
      float ms=sigm(i2+h2a[r]);
      zreg[r]=(1.0f-ms)*zreg[r]+ms*ftanh(i3+h3a[r]);
    }
    { int2 zz; zz.x=pack2bf(zreg[0],zreg[1]); zz.y=pack2bf(zreg[2],zreg[3]);
      *(int2*)&z16[node*128 + wrslot]=zz; }
    __syncthreads();
    f32x4 zw={0.f,0.f,0.f,0.f};
    #pragma unroll
    for(int kk=0;kk<4;++kk){
      short8 zb=*(const short8*)&z16[node*128 + ((kk*32 + q*8) ^ (n7<<3))];
      zw=__builtin_amdgcn_mfma_f32_16x16x32_bf16(wzf[kk],zb,zw,0,0,0);
    }
    #pragma unroll
    for(int r=0;r<4;++r)
      yreg[r]=(1.0f-msb[r])*yreg[r]+msb[r]*ftanh(zw[r]+i4s[r]);
    { int2 yy; yy.x=pack2bf(yreg[0],yreg[1]); yy.y=pack2bf(yreg[2],yreg[3]);
      *(int2*)&y16[node*128 + wrslot]=yy; }
    __syncthreads();
  }

  // MLP1
  {
    short8 w1f[4];
    #pragma unroll
    for(int kk=0;kk<4;++kk)
      w1f[kk]=*(const short8*)(w1b + (w*16 + node)*128 + kk*32 + q*8);
    float4 b1v=*(const float4*)(b1 + w*16 + q*4);
    f32x4 a={0.f,0.f,0.f,0.f};
    #pragma unroll
    for(int kk=0;kk<4;++kk){
      short8 yb=*(const short8*)&y16[node*128 + ((kk*32 + q*8) ^ (n7<<3))];
      a=__builtin_amdgcn_mfma_f32_16x16x32_bf16(w1f[kk],yb,a,0,0,0);
    }
    float t0=swishf(a[0]+b1v.x), t1=swishf(a[1]+b1v.y);
    float t2=swishf(a[2]+b1v.z), t3=swishf(a[3]+b1v.w);
    int2 zz; zz.x=pack2bf(t0,t1); zz.y=pack2bf(t2,t3);
    *(int2*)&z16[node*128 + wrslot]=zz;
  }
  __syncthreads();
  // MLP2 -> hstg (fp32) + h16 (bf16 swizzled)
  {
    short8 w2f[4];
    #pragma unroll
    for(int kk=0;kk<4;++kk)
      w2f[kk]=*(const short8*)(w2b + (w*16 + node)*128 + kk*32 + q*8);
    float4 b2v=*(const float4*)(b2 + w*16 + q*4);
    f32x4 a={0.f,0.f,0.f,0.f};
    #pragma unroll
    for(int kk=0;kk<4;++kk){
      short8 zb=*(const short8*)&z16[node*128 + ((kk*32 + q*8) ^ (n7<<3))];
      a=__builtin_amdgcn_mfma_f32_16x16x32_bf16(w2f[kk],zb,a,0,0,0);
    }
    float h0=swishf(a[0]+b2v.x), h1=swishf(a[1]+b2v.y);
    float h2=swishf(a[2]+b2v.z), h3=swishf(a[3]+b2v.w);
    hstg[node*132 + w*16+q*4+0]=h0;
    hstg[node*132 + w*16+q*4+1]=h1;
    hstg[node*132 + w*16+q*4+2]=h2;
    hstg[node*132 + w*16+q*4+3]=h3;
    int2 hb; hb.x=pack2bf(h0,h1); hb.y=pack2bf(h2,h3);
    *(int2*)&h16[node*128 + wrslot]=hb;
  }
  __syncthreads();
  for(int i=tid;i<16*128;i+=512){
    int nn=i>>7, ff=i&127;
    hout[(n0+nn)*128+ff]=hstg[nn*132+ff];
  }
  transform_phase(tid,n0,h16,xts,ssred,sdred,wl,a_sg,a_dg,a_sm,a_dm,gsc_g,gsc_m,xt_out,ss_out,sd_out);
}

// ---------------- fused: aggregate(layer l) + transform(layer l+1) ----------------
__global__ __launch_bounds__(512,2) void gat_fused_kernel(
    const int* __restrict__ rowptr, const int* __restrict__ csr_src,
    const short* __restrict__ xt_in, const float* __restrict__ ss_in, const float* __restrict__ sd_in,
    const float* __restrict__ bias_g, const float* __restrict__ bias_m,
    float* __restrict__ h,
    const short* __restrict__ wl,
    const float* __restrict__ a_sg, const float* __restrict__ a_dg,
    const float* __restrict__ a_sm, const float* __restrict__ a_dm,
    const float* __restrict__ gsc_g, const float* __restrict__ gsc_m,
    short* __restrict__ xt_out, float* __restrict__ ss_out, float* __restrict__ sd_out)
{
  __shared__ short h16[16*128];
  __shared__ short xts[16*256];
  __shared__ float ssred[128], sdred[128];
  const int tid=threadIdx.x, lane=tid&63, w=tid>>6;
  const int n0=blockIdx.x*16;
  #pragma unroll
  for(int which=0;which<2;++which){
    int row=w*2+which, n=n0+row;
    float4 hv=aggregate_node(n,lane,rowptr,csr_src,xt_in,ss_in,sd_in,bias_g,bias_m,h);
    if(lane<32){
      *(float4*)(h+(size_t)n*128+4*lane)=hv;
      int2 hb; hb.x=pack2bf(hv.x,hv.y); hb.y=pack2bf(hv.z,hv.w);
      *(int2*)&h16[row*128 + ((4*lane) ^ ((row&7)<<3))]=hb;
    }
  }
  transform_phase(tid,n0,h16,xts,ssred,sdred,wl,a_sg,a_dg,a_sm,a_dm,gsc_g,gsc_m,xt_out,ss_out,sd_out);
}

// ---------------- fused: aggregate(layer 5) + decoder ----------------
__global__ __launch_bounds__(512,2) void gat_last_decoder_kernel(
    const int* __restrict__ rowptr, const int* __restrict__ csr_src,
    const short* __restrict__ xt_in, const float* __restrict__ ss_in, const float* __restrict__ sd_in,
    const float* __restrict__ bias_g, const float* __restrict__ bias_m,
    const float* __restrict__ h, const float* __restrict__ u,
    const float* __restrict__ Wd, const float* __restrict__ bd,
    const float* __restrict__ w1, const float* __restrict__ b1,
    const float* __restrict__ w2, const float* __restrict__ b2,
    float* __restrict__ out)
{
  __shared__ float hdec[16*128];
  __shared__ float h2[16][2][128];
  __shared__ float c1[16][8][38];
  __shared__ float w1s[256], w2s[224], b1s[8], b2s[2];
  const int tid=threadIdx.x, lane=tid&63, w=tid>>6;
  const int n0=blockIdx.x*16;
  if(tid<256) w1s[tid]=w1[tid];
  else if(tid<480) w2s[tid-256]=w2[tid-256];
  else if(tid<488) b1s[tid-480]=b1[tid-480];
  else if(tid<490) b2s[tid-488]=b2[tid-488];
  #pragma unroll
  for(int which=0;which<2;++which){
    int row=w*2+which, n=n0+row;
    float4 hv=aggregate_node(n,lane,rowptr,csr_src,xt_in,ss_in,sd_in,bias_g,bias_m,h);
    if(lane<32) *(float4*)&hdec[row*128+4*lane]=hv;
  }
  __syncthreads();
  {
    int o=tid&255, grp=tid>>8;
    const float4* wp=(const float4*)(Wd + o*128);
    float acc[8];
    #pragma unroll
    for(int n=0;n<8;++n) acc[n]=0.f;
    for(int k=0;k<32;++k){
      float4 wv=wp[k];
      #pragma unroll
      for(int n=0;n<8;++n){ float4 hval=*(const float4*)&hdec[(grp*8+n)*128+k*4]; acc[n]+=dot4(wv,hval); }
    }
    float bdv=bd[o];
    int chn=o>>7, p=o&127;
    #pragma unroll
    for(int n=0;n<8;++n) h2[grp*8+n][chn][p]=swishf(acc[n]+bdv);
  }
  __syncthreads();
  for(int idx=tid; idx<16*8*38; idx+=512){
    int n=idx/(8*38); int r=idx%(8*38); int oc=r/38, p=r%38;
    float acc=b1s[oc];
    const float* ww=&w1s[oc*32];
    #pragma unroll
    for(int ic=0;ic<2;++ic)
      #pragma unroll
      for(int k=0;k<16;++k) acc+=ww[ic*16+k]*h2[n][ic][3*p+k];
    c1[n][oc][p]=swishf(acc);
  }
  __syncthreads();
  for(int idx=tid; idx<16*2*25; idx+=512){
    int n=idx/50; int r=idx%50; int oc=r/25, p=r%25;
    float acc=b2s[oc];
    const float* ww=&w2s[oc*112];
    #pragma unroll
    for(int ic=0;ic<8;++ic)
      #pragma unroll
      for(int k=0;k<14;++k) acc+=ww[ic*14+k]*c1[n][ic][p+k];
    int col=oc*25+p;
    out[(n0+n)*50+col]=u[(n0+n)*50+col]+0.04f*(float)(p+1)*acc;
  }
}

extern "C" void kernel_launch(void* const* d_in, const int* in_sizes, int n_in,
                              void* d_out, int out_size, void* d_ws, size_t ws_size,
                              hipStream_t stream)
{
  const float* u          =(const float*)d_in[0];
  const float* pos        =(const float*)d_in[1];
  const int*   ei         =(const int*)d_in[2];
  const float* lem_inp_w  =(const float*)d_in[3];
  const float* lem_inp_b  =(const float*)d_in[4];
  const float* lem_hid_w  =(const float*)d_in[5];
  const float* lem_hid_b  =(const float*)d_in[6];
  const float* lem_z_w    =(const float*)d_in[7];
  const float* lem_z_b    =(const float*)d_in[8];
  const float* mlp1_w     =(const float*)d_in[9];
  const float* mlp1_b     =(const float*)d_in[10];
  const float* mlp2_w     =(const float*)d_in[11];
  const float* mlp2_b     =(const float*)d_in[12];
  const float* gnn_lin_w  =(const float*)d_in[13];
  const float* gnn_edge_w =(const float*)d_in[14];
  const float* gnn_att_src=(const float*)d_in[15];
  const float* gnn_att_dst=(const float*)d_in[16];
  const float* gnn_att_edge=(const float*)d_in[17];
  const float* gnn_bias   =(const float*)d_in[18];
  const float* gate_lin_w =(const float*)d_in[19];
  const float* gate_edge_w=(const float*)d_in[20];
  const float* gate_att_src=(const float*)d_in[21];
  const float* gate_att_dst=(const float*)d_in[22];
  const float* gate_att_edge=(const float*)d_in[23];
  const float* gate_bias  =(const float*)d_in[24];
  const float* dbl_w      =(const float*)d_in[25];
  const float* dbl_b      =(const float*)d_in[26];
  const float* conv1_w    =(const float*)d_in[27];
  const float* conv1_b    =(const float*)d_in[28];
  const float* conv2_w    =(const float*)d_in[29];
  const float* conv2_b    =(const float*)d_in[30];
  float* out=(float*)d_out;

  char* ws=(char*)d_ws;
  size_t off=0;
  auto alloc=[&](size_t bytes)->char*{ char* p=ws+off; off+=(bytes+255)&~(size_t)255; return p; };
  float* h    =(float*)alloc((size_t)N_NODES*128*4);
  short* xtA  =(short*)alloc((size_t)N_NODES*256*2);
  short* xtB  =(short*)alloc((size_t)N_NODES*256*2);
  float* ssA  =(float*)alloc((size_t)N_NODES*2*4);
  float* ssB  =(float*)alloc((size_t)N_NODES*2*4);
  float* sdA  =(float*)alloc((size_t)N_NODES*2*4);
  float* sdB  =(float*)alloc((size_t)N_NODES*2*4);
  float* gsc  =(float*)alloc((size_t)12*N_NODES*4);
  float* wearr=(float*)alloc(12*51*4);
  int* cnt    =(int*)alloc(N_NODES*4);
  int* rowptr =(int*)alloc((N_NODES+8)*4);
  int* cursor =(int*)alloc(N_NODES*4);
  int* csrsrc =(int*)alloc((size_t)N_EDGES*4);
  short* whb  =(short*)alloc(384*128*2);
  short* wzb  =(short*)alloc(128*128*2);
  short* w1b  =(short*)alloc(128*128*2);
  short* w2b  =(short*)alloc(128*128*2);
  short* wlin16=(short*)alloc((size_t)6*2*128*128*2);

  const int* src=ei;
  const int* dst=ei+N_EDGES;

  hipMemsetAsync(cnt,0,N_NODES*4,stream);
  hist_kernel<<<N_EDGES/256,256,0,stream>>>(dst,cnt);
  scan_kernel<<<1,1024,0,stream>>>(cnt,rowptr,cursor);
  scatter_kernel<<<N_EDGES/256,256,0,stream>>>(src,dst,cursor,csrsrc);
  prep_bf16_kernel<<<(294912+255)/256,256,0,stream>>>(lem_hid_w,lem_z_w,mlp1_w,mlp2_w,
                                                      gate_lin_w,gnn_lin_w,
                                                      whb,wzb,w1b,w2b,wlin16);
  we_kernel<<<3,256,0,stream>>>(gate_edge_w,gnn_edge_w,gate_att_edge,gnn_att_edge,wearr);
  gsc_kernel<<<N_NODES/128,128,0,stream>>>(u,pos,wearr,gsc);

  short* xtbuf[2]={xtA,xtB};
  float* ssbuf[2]={ssA,ssB};
  float* sdbuf[2]={sdA,sdB};

  lem_t0_kernel<<<N_NODES/16,512,0,stream>>>(u,pos,lem_inp_w,lem_inp_b,whb,lem_hid_b,
      wzb,lem_z_b,w1b,mlp1_b,w2b,mlp2_b,h,
      wlin16,
      gate_att_src, gate_att_dst, gnn_att_src, gnn_att_dst,
      gsc, gsc+(size_t)N_NODES,
      xtbuf[0], ssbuf[0], sdbuf[0]);

  for(int l=0;l<5;++l){
    int in=l&1, o2=(l+1)&1;
    gat_fused_kernel<<<N_NODES/16,512,0,stream>>>(rowptr,csrsrc,
      xtbuf[in],ssbuf[in],sdbuf[in],
      gate_bias+l*128, gnn_bias+l*128, h,
      wlin16+(size_t)(l+1)*2*16384,
      gate_att_src+(l+1)*128, gate_att_dst+(l+1)*128,
      gnn_att_src+(l+1)*128, gnn_att_dst+(l+1)*128,
      gsc+(size_t)(2*(l+1))*N_NODES, gsc+(size_t)(2*(l+1)+1)*N_NODES,
      xtbuf[o2], ssbuf[o2], sdbuf[o2]);
  }

  gat_last_decoder_kernel<<<N_NODES/16,512,0,stream>>>(rowptr,csrsrc,
      xtbuf[1],ssbuf[1],sdbuf[1],
      gate_bias+5*128, gnn_bias+5*128, h, u,
      dbl_w, dbl_b, conv1_w, conv1_b, conv2_w, conv2_b, out);
}

// Round 6
// 358.362 us; speedup vs baseline: 4.8166x; 1.0494x over previous
//
#include <hip/hip_runtime.h>

#define N_NODES 8192
#define N_EDGES 131072

using short8 = __attribute__((ext_vector_type(8))) short;
using f32x4  = __attribute__((ext_vector_type(4))) float;

__device__ __forceinline__ float rcpf(float x){ return __builtin_amdgcn_rcpf(x); }
__device__ __forceinline__ float sigm(float x){ return rcpf(1.0f+__expf(-x)); }
__device__ __forceinline__ float ftanh(float x){ float e=__expf(2.0f*x); return (e-1.0f)*rcpf(e+1.0f); }
__device__ __forceinline__ float swishf(float x){ return x*sigm(x); }
__device__ __forceinline__ float leaky(float x){ return x>=0.0f? x : 0.2f*x; }
__device__ __forceinline__ float dot4(float4 a, float4 b){ return a.x*b.x+a.y*b.y+a.z*b.z+a.w*b.w; }
__device__ __forceinline__ short f2bf(float x){
  unsigned u=__float_as_uint(x);
  unsigned r=(u + 0x7fffu + ((u>>16)&1u))>>16;
  return (short)r;
}
// packed bf16 convert: low16 = bf16(a), high16 = bf16(b), RNE
__device__ __forceinline__ int cvtpk(float a, float b){
  int r; asm("v_cvt_pk_bf16_f32 %0, %1, %2" : "=v"(r) : "v"(a), "v"(b)); return r;
}

__device__ __forceinline__ float wave_rsum(float v){
  #pragma unroll
  for(int m=32;m;m>>=1) v+=__shfl_xor(v,m);
  return v;
}

// ---------------- CSR build ----------------
__global__ __launch_bounds__(256) void hist_kernel(const int* __restrict__ dst, int* __restrict__ cnt){
  int e=blockIdx.x*256+threadIdx.x;
  if(e<N_EDGES) atomicAdd(&cnt[dst[e]],1);
}

__global__ __launch_bounds__(1024) void scan_kernel(const int* __restrict__ cnt, int* __restrict__ rowptr, int* __restrict__ cursor){
  __shared__ int sums[1024];
  int t=threadIdx.x; int base=t*8;
  int local[8]; int s=0;
  #pragma unroll
  for(int i=0;i<8;++i){ local[i]=s; s+=cnt[base+i]; }
  sums[t]=s; __syncthreads();
  for(int off=1;off<1024;off<<=1){
    int v=(t>=off)?sums[t-off]:0;
    __syncthreads();
    sums[t]+=v;
    __syncthreads();
  }
  int offset=(t>0)?sums[t-1]:0;
  #pragma unroll
  for(int i=0;i<8;++i){ int v=offset+local[i]; rowptr[base+i]=v; cursor[base+i]=v; }
  if(t==1023) rowptr[N_NODES]=sums[1023];
}

__global__ __launch_bounds__(256) void scatter_kernel(const int* __restrict__ src, const int* __restrict__ dst,
                                                      int* __restrict__ cursor, int* __restrict__ csr_src){
  int e=blockIdx.x*256+threadIdx.x;
  if(e<N_EDGES){
    int slot=atomicAdd(&cursor[dst[e]],1);
    csr_src[slot]=src[e];
  }
}

// ---------------- fused fp32 -> bf16 weight prep + edge-weight collapse ----------------
__global__ __launch_bounds__(256) void prep_bf16_kernel(
    const float* __restrict__ lem_hid_w, const float* __restrict__ lem_z_w,
    const float* __restrict__ mlp1_w, const float* __restrict__ mlp2_w,
    const float* __restrict__ gate_lin_w, const float* __restrict__ gnn_lin_w,
    const float* __restrict__ gate_ew, const float* __restrict__ gnn_ew,
    const float* __restrict__ gate_ae, const float* __restrict__ gnn_ae,
    short* __restrict__ whb, short* __restrict__ wzb, short* __restrict__ w1b,
    short* __restrict__ w2b, short* __restrict__ wlin16, float* __restrict__ we)
{
  int i=blockIdx.x*256+threadIdx.x;
  if(i<49152){ whb[i]=f2bf(lem_hid_w[i]); return; }
  if(i<65536){ int k=i-49152; wzb[k]=f2bf(lem_z_w[k]); return; }
  if(i<81920){ int k=i-65536; w1b[k]=f2bf(mlp1_w[k]); return; }
  if(i<98304){ int k=i-81920; w2b[k]=f2bf(mlp2_w[k]); return; }
  if(i<294912){
    int k=i-98304;                 // [6][2][16384]
    int l=k>>15, which=(k>>14)&1, r=k&16383;
    const float* s = which? gnn_lin_w + l*16384 + r : gate_lin_w + l*16384 + r;
    wlin16[k]=f2bf(*s);
    return;
  }
  int idx=i-294912;
  if(idx>=12*51) return;
  int g=idx/51, k=idx%51, l=g>>1;
  const float* ew = (g&1)? gnn_ew + l*128*51 : gate_ew + l*128*51;
  const float* ae = (g&1)? gnn_ae + l*128    : gate_ae + l*128;
  float s=0.f;
  for(int f=0;f<128;++f) s+=ew[f*51+k]*ae[f];
  we[idx]=s;
}

__global__ __launch_bounds__(128) void gsc_kernel(const float* __restrict__ u, const float* __restrict__ pos,
                                                  const float* __restrict__ we, float* __restrict__ gsc){
  int n=blockIdx.x*128+threadIdx.x;
  float uv[50];
  #pragma unroll
  for(int k=0;k<50;++k) uv[k]=u[n*50+k];
  float px=pos[n*2+1]*(1.0f/16.0f);
  for(int g=0;g<12;++g){
    const float* w=we+g*51;
    float s=w[50]*px;
    #pragma unroll
    for(int k=0;k<50;++k) s+=w[k]*uv[k];
    gsc[g*N_NODES+n]=s;
  }
}

// ---------------- shared device pieces ----------------
// GAT transform for 16 nodes (h16 = bf16 swizzled [16][128]); 8 waves.
__device__ __forceinline__ void transform_phase(
    int tid, int n0,
    const short* __restrict__ h16, short* __restrict__ xts,
    float* __restrict__ ssred, float* __restrict__ sdred,
    const short* __restrict__ wl,
    const float* __restrict__ a_sg, const float* __restrict__ a_dg,
    const float* __restrict__ a_sm, const float* __restrict__ a_dm,
    const float* __restrict__ gsc_g, const float* __restrict__ gsc_m,
    short* __restrict__ xt_out, float* __restrict__ ss_out, float* __restrict__ sd_out)
{
  const int lane=tid&63, w=tid>>6;
  const int cg=w&1, ch=w>>1;
  const int r16=lane&15, kq=lane>>4;
  __syncthreads();
  short8 afr[4];
  #pragma unroll
  for(int kk=0;kk<4;++kk)
    afr[kk]=*(const short8*)&h16[r16*128 + ((kk*32+kq*8) ^ ((r16&7)<<3))];
  const short* wb = wl + cg*16384;
  const float* as_ = cg? a_sm : a_sg;
  const float* ad_ = cg? a_dm : a_dg;
  float ssp[4]={0,0,0,0}, sdp[4]={0,0,0,0};
  #pragma unroll
  for(int ci=0;ci<2;++ci){
    int c0=(ch*2+ci)*16;
    f32x4 acc={0.f,0.f,0.f,0.f};
    #pragma unroll
    for(int kk=0;kk<4;++kk){
      short8 b=*(const short8*)(wb + (c0+r16)*128 + kk*32 + kq*8);
      acc=__builtin_amdgcn_mfma_f32_16x16x32_bf16(afr[kk],b,acc,0,0,0);
    }
    float av=as_[c0+r16], dv=ad_[c0+r16];
    #pragma unroll
    for(int r=0;r<4;++r){
      ssp[r]+=acc[r]*av; sdp[r]+=acc[r]*dv;
      xts[(kq*4+r)*256 + cg*128 + c0 + r16]=f2bf(acc[r]);
    }
  }
  #pragma unroll
  for(int m=1;m<16;m<<=1){
    #pragma unroll
    for(int r=0;r<4;++r){ ssp[r]+=__shfl_xor(ssp[r],m); sdp[r]+=__shfl_xor(sdp[r],m); }
  }
  if(r16==0){
    #pragma unroll
    for(int r=0;r<4;++r){ ssred[w*16+kq*4+r]=ssp[r]; sdred[w*16+kq*4+r]=sdp[r]; }
  }
  __syncthreads();
  if(tid<32){
    int node=tid&15, cg2=tid>>4;
    float sv=0.f, dv=0.f;
    #pragma unroll
    for(int c2=0;c2<4;++c2){ sv+=ssred[(c2*2+cg2)*16+node]; dv+=sdred[(c2*2+cg2)*16+node]; }
    float gv=(cg2? gsc_m:gsc_g)[n0+node];
    ss_out[2*(n0+node)+cg2]=sv+gv;
    sd_out[2*(n0+node)+cg2]=dv-gv;
  }
  {
    const short8* sp=(const short8*)xts;
    short8* dp=(short8*)(xt_out + (size_t)n0*256);
    dp[tid]=sp[tid];
  }
}

// Dual-GAT softmax aggregate for one node by one wave (single-pass, no max).
// softmax is shift-invariant; clamp at 60 guards overflow (exp(60)=1.1e26, sum << fp32 max).
__device__ __forceinline__ float4 aggregate_node(
    int n, int lane,
    const int* __restrict__ rowptr, const int* __restrict__ csr_src,
    const short* __restrict__ xt_in, const float* __restrict__ ss_in, const float* __restrict__ sd_in,
    const float* __restrict__ bias_g, const float* __restrict__ bias_m,
    const float* __restrict__ h)
{
  const int s0=rowptr[n], deg=rowptr[n+1]-s0;
  const float2 sdv=*(const float2*)(sd_in+2*n);
  const float bg=sdv.x, bm=sdv.y;
  float dg=0.f,dm=0.f, acc0=0.f,acc1=0.f,acc2=0.f,acc3=0.f;
  for(int c=0;c<deg;c+=64){
    int i=c+lane, s=0; float eg=0.f, em=0.f;
    if(i<deg){
      s=csr_src[s0+i];
      float2 ssv=*(const float2*)(ss_in+2*s);
      eg=__expf(fminf(leaky(ssv.x+bg),60.f));
      em=__expf(fminf(leaky(ssv.y+bm),60.f));
      dg+=eg; dm+=em;
    }
    int cntc=min(64,deg-c);
    for(int cb=0;cb<cntc;cb+=8){
      int sj[8]; float wj[8];
      #pragma unroll
      for(int jj=0;jj<8;++jj){
        int sv=__shfl(s,cb+jj);
        float wg=__shfl(eg,cb+jj), wm=__shfl(em,cb+jj);
        sj[jj]=sv;
        wj[jj]= lane<32? wg : wm;
      }
      uint2 rows[8];
      #pragma unroll
      for(int jj=0;jj<8;++jj)
        rows[jj]=*(const uint2*)(xt_in + (size_t)sj[jj]*256 + 4*lane);
      #pragma unroll
      for(int jj=0;jj<8;++jj){
        float wv=wj[jj];
        unsigned p0=rows[jj].x, p1=rows[jj].y;
        acc0+=wv*__uint_as_float(p0<<16);
        acc1+=wv*__uint_as_float(p0&0xffff0000u);
        acc2+=wv*__uint_as_float(p1<<16);
        acc3+=wv*__uint_as_float(p1&0xffff0000u);
      }
    }
  }
  dg=wave_rsum(dg); dm=wave_rsum(dm);
  float rr = lane<32? rcpf(dg+1e-16f) : rcpf(dm+1e-16f);
  const float* bp = lane<32? bias_g+4*lane : bias_m+4*(lane-32);
  float4 bv=*(const float4*)bp;
  float o0=acc0*rr+bv.x, o1=acc1*rr+bv.y, o2=acc2*rr+bv.z, o3=acc3*rr+bv.w;
  float s0_=sigm(o0), s1_=sigm(o1), s2_=sigm(o2), s3_=sigm(o3);
  float v0=lane<32? s0_:o0*s0_;
  float v1=lane<32? s1_:o1*s1_;
  float v2=lane<32? s2_:o2*s2_;
  float v3=lane<32? s3_:o3*s3_;
  float m0=__shfl_xor(v0,32), m1=__shfl_xor(v1,32), m2=__shfl_xor(v2,32), m3=__shfl_xor(v3,32);
  float4 r;
  if(lane<32){
    float4 hv=*(const float4*)(h + (size_t)n*128 + 4*lane);
    r.x=(1.0f-v0)*hv.x+v0*m0;
    r.y=(1.0f-v1)*hv.y+v1*m1;
    r.z=(1.0f-v2)*hv.z+v2*m2;
    r.w=(1.0f-v3)*hv.w+v3*m3;
  } else { r.x=r.y=r.z=r.w=0.f; }
  return r;
}

// ---------------- LEM scan (MFMA, 32 nodes/block) + MLP + GAT transform layer 0 ----------------
// 512 threads = 8 waves; two 16-node tiles processed between the same 2 barriers/step.
__global__ __launch_bounds__(512,2) void lem_t0_kernel(
    const float* __restrict__ u, const float* __restrict__ pos,
    const float* __restrict__ Wi, const float* __restrict__ bi,
    const short* __restrict__ whb, const float* __restrict__ bh,
    const short* __restrict__ wzb, const float* __restrict__ bz,
    const short* __restrict__ w1b, const float* __restrict__ b1,
    const short* __restrict__ w2b, const float* __restrict__ b2,
    float* __restrict__ hout,
    const short* __restrict__ wl,
    const float* __restrict__ a_sg, const float* __restrict__ a_dg,
    const float* __restrict__ a_sm, const float* __restrict__ a_dm,
    const float* __restrict__ gsc_g, const float* __restrict__ gsc_m,
    short* __restrict__ xt_out, float* __restrict__ ss_out, float* __restrict__ sd_out)
{
  __shared__ short y16[2][16*128];
  __shared__ short z16[2][16*128];
  __shared__ float u_s[32*50];
  __shared__ short h16[16*128];
  __shared__ short xts[16*256];
  __shared__ float ssred[128], sdred[128];

  const int tid=threadIdx.x, lane=tid&63, w=tid>>6;
  const int node=lane&15, q=lane>>4;
  const int n7=node&7;
  const int n0=blockIdx.x*32;

  for(int i=tid;i<32*50;i+=512) u_s[i]=u[n0*50+i];
  for(int i=tid;i<2*16*64;i+=512) ((int*)y16)[i]=0;

  const float px0=pos[(n0+node)*2+1]*(1.0f/16.0f),    pt0=pos[(n0+node)*2+0]*0.25f;
  const float px1=pos[(n0+16+node)*2+1]*(1.0f/16.0f), pt1=pos[(n0+16+node)*2+0]*0.25f;

  // per-lane input coefficients for features fr = w*16+q*4+r, gates 0..3
  float bb[4][4], wix[4][4], wiw[4][4], wiy[4][4], wiz[4][4];
  #pragma unroll
  for(int gg=0; gg<4; ++gg){
    #pragma unroll
    for(int r=0;r<4;++r){
      int fr = w*16+q*4+r;
      int row = gg*128+fr;
      float4 wi = *(const float4*)(Wi+4*row);
      bb[gg][r] = bi[row] + ((gg<3)? bh[row] : bz[fr]);
      wix[gg][r]=wi.x; wiw[gg][r]=wi.w; wiy[gg][r]=wi.y; wiz[gg][r]=wi.z;
    }
  }

  short8 whf[3][4];
  #pragma unroll
  for(int gg=0;gg<3;++gg)
    #pragma unroll
    for(int kk=0;kk<4;++kk)
      whf[gg][kk]=*(const short8*)(whb + (gg*128 + w*16 + node)*128 + kk*32 + q*8);
  short8 wzf[4];
  #pragma unroll
  for(int kk=0;kk<4;++kk)
    wzf[kk]=*(const short8*)(wzb + (w*16 + node)*128 + kk*32 + q*8);

  float yr0[4]={0.f,0.f,0.f,0.f}, zr0[4]={0.f,0.f,0.f,0.f};
  float yr1[4]={0.f,0.f,0.f,0.f}, zr1[4]={0.f,0.f,0.f,0.f};
  float msb0[4], i4s0[4], msb1[4], i4s1[4];
  const int wrslot = (w*16+q*4) ^ (n7<<3);
  const int rdbase = n7<<3;
  __syncthreads();

  for(int t=0;t<25;++t){
    const float tf=(float)(t+1);
    // ---- Phase A tile 0 ----
    {
      f32x4 h1a={0.f,0.f,0.f,0.f}, h2a=h1a, h3a=h1a;
      #pragma unroll
      for(int kk=0;kk<4;++kk){
        short8 yb=*(const short8*)&y16[0][node*128 + ((kk*32 + q*8) ^ rdbase)];
        h1a=__builtin_amdgcn_mfma_f32_16x16x32_bf16(whf[0][kk],yb,h1a,0,0,0);
        h2a=__builtin_amdgcn_mfma_f32_16x16x32_bf16(whf[1][kk],yb,h2a,0,0,0);
        h3a=__builtin_amdgcn_mfma_f32_16x16x32_bf16(whf[2][kk],yb,h3a,0,0,0);
      }
      const float u0=u_s[node*50+t], u1=u_s[node*50+25+t];
      const float ts=pt0+0.04f*tf;
      #pragma unroll
      for(int r=0;r<4;++r){
        float i1=bb[0][r]+wix[0][r]*px0+wiw[0][r]*ts+wiy[0][r]*u0+wiz[0][r]*u1;
        float i2=bb[1][r]+wix[1][r]*px0+wiw[1][r]*ts+wiy[1][r]*u0+wiz[1][r]*u1;
        float i3=bb[2][r]+wix[2][r]*px0+wiw[2][r]*ts+wiy[2][r]*u0+wiz[2][r]*u1;
        i4s0[r] =bb[3][r]+wix[3][r]*px0+wiw[3][r]*ts+wiy[3][r]*u0+wiz[3][r]*u1;
        msb0[r]=sigm(i1+h1a[r]);
        float ms=sigm(i2+h2a[r]);
        zr0[r]=(1.0f-ms)*zr0[r]+ms*ftanh(i3+h3a[r]);
      }
      int2 zz; zz.x=cvtpk(zr0[0],zr0[1]); zz.y=cvtpk(zr0[2],zr0[3]);
      *(int2*)&z16[0][node*128 + wrslot]=zz;
    }
    // ---- Phase A tile 1 ----
    {
      f32x4 h1a={0.f,0.f,0.f,0.f}, h2a=h1a, h3a=h1a;
      #pragma unroll
      for(int kk=0;kk<4;++kk){
        short8 yb=*(const short8*)&y16[1][node*128 + ((kk*32 + q*8) ^ rdbase)];
        h1a=__builtin_amdgcn_mfma_f32_16x16x32_bf16(whf[0][kk],yb,h1a,0,0,0);
        h2a=__builtin_amdgcn_mfma_f32_16x16x32_bf16(whf[1][kk],yb,h2a,0,0,0);
        h3a=__builtin_amdgcn_mfma_f32_16x16x32_bf16(whf[2][kk],yb,h3a,0,0,0);
      }
      const float u0=u_s[(16+node)*50+t], u1=u_s[(16+node)*50+25+t];
      const float ts=pt1+0.04f*tf;
      #pragma unroll
      for(int r=0;r<4;++r){
        float i1=bb[0][r]+wix[0][r]*px1+wiw[0][r]*ts+wiy[0][r]*u0+wiz[0][r]*u1;
        float i2=bb[1][r]+wix[1][r]*px1+wiw[1][r]*ts+wiy[1][r]*u0+wiz[1][r]*u1;
        float i3=bb[2][r]+wix[2][r]*px1+wiw[2][r]*ts+wiy[2][r]*u0+wiz[2][r]*u1;
        i4s1[r] =bb[3][r]+wix[3][r]*px1+wiw[3][r]*ts+wiy[3][r]*u0+wiz[3][r]*u1;
        msb1[r]=sigm(i1+h1a[r]);
        float ms=sigm(i2+h2a[r]);
        zr1[r]=(1.0f-ms)*zr1[r]+ms*ftanh(i3+h3a[r]);
      }
      int2 zz; zz.x=cvtpk(zr1[0],zr1[1]); zz.y=cvtpk(zr1[2],zr1[3]);
      *(int2*)&z16[1][node*128 + wrslot]=zz;
    }
    __syncthreads();
    // ---- Phase C tile 0 ----
    {
      f32x4 zw={0.f,0.f,0.f,0.f};
      #pragma unroll
      for(int kk=0;kk<4;++kk){
        short8 zb=*(const short8*)&z16[0][node*128 + ((kk*32 + q*8) ^ rdbase)];
        zw=__builtin_amdgcn_mfma_f32_16x16x32_bf16(wzf[kk],zb,zw,0,0,0);
      }
      #pragma unroll
      for(int r=0;r<4;++r)
        yr0[r]=(1.0f-msb0[r])*yr0[r]+msb0[r]*ftanh(zw[r]+i4s0[r]);
      int2 yy; yy.x=cvtpk(yr0[0],yr0[1]); yy.y=cvtpk(yr0[2],yr0[3]);
      *(int2*)&y16[0][node*128 + wrslot]=yy;
    }
    // ---- Phase C tile 1 ----
    {
      f32x4 zw={0.f,0.f,0.f,0.f};
      #pragma unroll
      for(int kk=0;kk<4;++kk){
        short8 zb=*(const short8*)&z16[1][node*128 + ((kk*32 + q*8) ^ rdbase)];
        zw=__builtin_amdgcn_mfma_f32_16x16x32_bf16(wzf[kk],zb,zw,0,0,0);
      }
      #pragma unroll
      for(int r=0;r<4;++r)
        yr1[r]=(1.0f-msb1[r])*yr1[r]+msb1[r]*ftanh(zw[r]+i4s1[r]);
      int2 yy; yy.x=cvtpk(yr1[0],yr1[1]); yy.y=cvtpk(yr1[2],yr1[3]);
      *(int2*)&y16[1][node*128 + wrslot]=yy;
    }
    __syncthreads();
  }

  // per node-tile: MLP1 -> MLP2 -> transform
  #pragma unroll
  for(int nt=0;nt<2;++nt){
    // MLP1: t1 = swish(W1 . y^T + b1) -> z16[nt]
    {
      short8 w1f[4];
      #pragma unroll
      for(int kk=0;kk<4;++kk)
        w1f[kk]=*(const short8*)(w1b + (w*16 + node)*128 + kk*32 + q*8);
      float4 b1v=*(const float4*)(b1 + w*16 + q*4);
      f32x4 a={0.f,0.f,0.f,0.f};
      #pragma unroll
      for(int kk=0;kk<4;++kk){
        short8 yb=*(const short8*)&y16[nt][node*128 + ((kk*32 + q*8) ^ rdbase)];
        a=__builtin_amdgcn_mfma_f32_16x16x32_bf16(w1f[kk],yb,a,0,0,0);
      }
      float t0=swishf(a[0]+b1v.x), t1=swishf(a[1]+b1v.y);
      float t2=swishf(a[2]+b1v.z), t3=swishf(a[3]+b1v.w);
      int2 zz; zz.x=cvtpk(t0,t1); zz.y=cvtpk(t2,t3);
      *(int2*)&z16[nt][node*128 + wrslot]=zz;
    }
    __syncthreads();
    // MLP2: h = swish(W2 . t1^T + b2) -> global + h16 (bf16 swizzled)
    {
      short8 w2f[4];
      #pragma unroll
      for(int kk=0;kk<4;++kk)
        w2f[kk]=*(const short8*)(w2b + (w*16 + node)*128 + kk*32 + q*8);
      float4 b2v=*(const float4*)(b2 + w*16 + q*4);
      f32x4 a={0.f,0.f,0.f,0.f};
      #pragma unroll
      for(int kk=0;kk<4;++kk){
        short8 zb=*(const short8*)&z16[nt][node*128 + ((kk*32 + q*8) ^ rdbase)];
        a=__builtin_amdgcn_mfma_f32_16x16x32_bf16(w2f[kk],zb,a,0,0,0);
      }
      float h0=swishf(a[0]+b2v.x), h1=swishf(a[1]+b2v.y);
      float h2=swishf(a[2]+b2v.z), h3=swishf(a[3]+b2v.w);
      float4 hv; hv.x=h0; hv.y=h1; hv.z=h2; hv.w=h3;
      *(float4*)(hout + (size_t)(n0+nt*16+node)*128 + w*16+q*4)=hv;
      int2 hb; hb.x=cvtpk(h0,h1); hb.y=cvtpk(h2,h3);
      *(int2*)&h16[node*128 + wrslot]=hb;
    }
    transform_phase(tid,n0+nt*16,h16,xts,ssred,sdred,wl,a_sg,a_dg,a_sm,a_dm,gsc_g,gsc_m,xt_out,ss_out,sd_out);
  }
}

// ---------------- fused: aggregate(layer l) + transform(layer l+1) ----------------
__global__ __launch_bounds__(512,2) void gat_fused_kernel(
    const int* __restrict__ rowptr, const int* __restrict__ csr_src,
    const short* __restrict__ xt_in, const float* __restrict__ ss_in, const float* __restrict__ sd_in,
    const float* __restrict__ bias_g, const float* __restrict__ bias_m,
    float* __restrict__ h,
    const short* __restrict__ wl,
    const float* __restrict__ a_sg, const float* __restrict__ a_dg,
    const float* __restrict__ a_sm, const float* __restrict__ a_dm,
    const float* __restrict__ gsc_g, const float* __restrict__ gsc_m,
    short* __restrict__ xt_out, float* __restrict__ ss_out, float* __restrict__ sd_out)
{
  __shared__ short h16[16*128];
  __shared__ short xts[16*256];
  __shared__ float ssred[128], sdred[128];
  const int tid=threadIdx.x, lane=tid&63, w=tid>>6;
  const int n0=blockIdx.x*16;
  #pragma unroll
  for(int which=0;which<2;++which){
    int row=w*2+which, n=n0+row;
    float4 hv=aggregate_node(n,lane,rowptr,csr_src,xt_in,ss_in,sd_in,bias_g,bias_m,h);
    if(lane<32){
      *(float4*)(h+(size_t)n*128+4*lane)=hv;
      int2 hb; hb.x=cvtpk(hv.x,hv.y); hb.y=cvtpk(hv.z,hv.w);
      *(int2*)&h16[row*128 + ((4*lane) ^ ((row&7)<<3))]=hb;
    }
  }
  transform_phase(tid,n0,h16,xts,ssred,sdred,wl,a_sg,a_dg,a_sm,a_dm,gsc_g,gsc_m,xt_out,ss_out,sd_out);
}

// ---------------- fused: aggregate(layer 5) + decoder ----------------
__global__ __launch_bounds__(512,2) void gat_last_decoder_kernel(
    const int* __restrict__ rowptr, const int* __restrict__ csr_src,
    const short* __restrict__ xt_in, const float* __restrict__ ss_in, const float* __restrict__ sd_in,
    const float* __restrict__ bias_g, const float* __restrict__ bias_m,
    const float* __restrict__ h, const float* __restrict__ u,
    const float* __restrict__ Wd, const float* __restrict__ bd,
    const float* __restrict__ w1, const float* __restrict__ b1,
    const float* __restrict__ w2, const float* __restrict__ b2,
    float* __restrict__ out)
{
  __shared__ float hdec[16*128];
  __shared__ float h2[16][2][128];
  __shared__ float c1[16][8][38];
  __shared__ float w1s[256], w2s[224], b1s[8], b2s[2];
  const int tid=threadIdx.x, lane=tid&63, w=tid>>6;
  const int n0=blockIdx.x*16;
  if(tid<256) w1s[tid]=w1[tid];
  else if(tid<480) w2s[tid-256]=w2[tid-256];
  else if(tid<488) b1s[tid-480]=b1[tid-480];
  else if(tid<490) b2s[tid-488]=b2[tid-488];
  #pragma unroll
  for(int which=0;which<2;++which){
    int row=w*2+which, n=n0+row;
    float4 hv=aggregate_node(n,lane,rowptr,csr_src,xt_in,ss_in,sd_in,bias_g,bias_m,h);
    if(lane<32) *(float4*)&hdec[row*128+4*lane]=hv;
  }
  __syncthreads();
  {
    int o=tid&255, grp=tid>>8;
    const float4* wp=(const float4*)(Wd + o*128);
    float acc[8];
    #pragma unroll
    for(int n=0;n<8;++n) acc[n]=0.f;
    for(int k=0;k<32;++k){
      float4 wv=wp[k];
      #pragma unroll
      for(int n=0;n<8;++n){ float4 hval=*(const float4*)&hdec[(grp*8+n)*128+k*4]; acc[n]+=dot4(wv,hval); }
    }
    float bdv=bd[o];
    int chn=o>>7, p=o&127;
    #pragma unroll
    for(int n=0;n<8;++n) h2[grp*8+n][chn][p]=swishf(acc[n]+bdv);
  }
  __syncthreads();
  for(int idx=tid; idx<16*8*38; idx+=512){
    int n=idx/(8*38); int r=idx%(8*38); int oc=r/38, p=r%38;
    float acc=b1s[oc];
    const float* ww=&w1s[oc*32];
    #pragma unroll
    for(int ic=0;ic<2;++ic)
      #pragma unroll
      for(int k=0;k<16;++k) acc+=ww[ic*16+k]*h2[n][ic][3*p+k];
    c1[n][oc][p]=swishf(acc);
  }
  __syncthreads();
  for(int idx=tid; idx<16*2*25; idx+=512){
    int n=idx/50; int r=idx%50; int oc=r/25, p=r%25;
    float acc=b2s[oc];
    const float* ww=&w2s[oc*112];
    #pragma unroll
    for(int ic=0;ic<8;++ic)
      #pragma unroll
      for(int k=0;k<14;++k) acc+=ww[ic*14+k]*c1[n][ic][p+k];
    int col=oc*25+p;
    out[(n0+n)*50+col]=u[(n0+n)*50+col]+0.04f*(float)(p+1)*acc;
  }
}

extern "C" void kernel_launch(void* const* d_in, const int* in_sizes, int n_in,
                              void* d_out, int out_size, void* d_ws, size_t ws_size,
                              hipStream_t stream)
{
  const float* u          =(const float*)d_in[0];
  const float* pos        =(const float*)d_in[1];
  const int*   ei         =(const int*)d_in[2];
  const float* lem_inp_w  =(const float*)d_in[3];
  const float* lem_inp_b  =(const float*)d_in[4];
  const float* lem_hid_w  =(const float*)d_in[5];
  const float* lem_hid_b  =(const float*)d_in[6];
  const float* lem_z_w    =(const float*)d_in[7];
  const float* lem_z_b    =(const float*)d_in[8];
  const float* mlp1_w     =(const float*)d_in[9];
  const float* mlp1_b     =(const float*)d_in[10];
  const float* mlp2_w     =(const float*)d_in[11];
  const float* mlp2_b     =(const float*)d_in[12];
  const float* gnn_lin_w  =(const float*)d_in[13];
  const float* gnn_edge_w =(const float*)d_in[14];
  const float* gnn_att_src=(const float*)d_in[15];
  const float* gnn_att_dst=(const float*)d_in[16];
  const float* gnn_att_edge=(const float*)d_in[17];
  const float* gnn_bias   =(const float*)d_in[18];
  const float* gate_lin_w =(const float*)d_in[19];
  const float* gate_edge_w=(const float*)d_in[20];
  const float* gate_att_src=(const float*)d_in[21];
  const float* gate_att_dst=(const float*)d_in[22];
  const float* gate_att_edge=(const float*)d_in[23];
  const float* gate_bias  =(const float*)d_in[24];
  const float* dbl_w      =(const float*)d_in[25];
  const float* dbl_b      =(const float*)d_in[26];
  const float* conv1_w    =(const float*)d_in[27];
  const float* conv1_b    =(const float*)d_in[28];
  const float* conv2_w    =(const float*)d_in[29];
  const float* conv2_b    =(const float*)d_in[30];
  float* out=(float*)d_out;

  char* ws=(char*)d_ws;
  size_t off=0;
  auto alloc=[&](size_t bytes)->char*{ char* p=ws+off; off+=(bytes+255)&~(size_t)255; return p; };
  float* h    =(float*)alloc((size_t)N_NODES*128*4);
  short* xtA  =(short*)alloc((size_t)N_NODES*256*2);
  short* xtB  =(short*)alloc((size_t)N_NODES*256*2);
  float* ssA  =(float*)alloc((size_t)N_NODES*2*4);
  float* ssB  =(float*)alloc((size_t)N_NODES*2*4);
  float* sdA  =(float*)alloc((size_t)N_NODES*2*4);
  float* sdB  =(float*)alloc((size_t)N_NODES*2*4);
  float* gsc  =(float*)alloc((size_t)12*N_NODES*4);
  float* wearr=(float*)alloc(12*51*4);
  int* cnt    =(int*)alloc(N_NODES*4);
  int* rowptr =(int*)alloc((N_NODES+8)*4);
  int* cursor =(int*)alloc(N_NODES*4);
  int* csrsrc =(int*)alloc((size_t)N_EDGES*4);
  short* whb  =(short*)alloc(384*128*2);
  short* wzb  =(short*)alloc(128*128*2);
  short* w1b  =(short*)alloc(128*128*2);
  short* w2b  =(short*)alloc(128*128*2);
  short* wlin16=(short*)alloc((size_t)6*2*128*128*2);

  const int* src=ei;
  const int* dst=ei+N_EDGES;

  hipMemsetAsync(cnt,0,N_NODES*4,stream);
  hist_kernel<<<N_EDGES/256,256,0,stream>>>(dst,cnt);
  scan_kernel<<<1,1024,0,stream>>>(cnt,rowptr,cursor);
  scatter_kernel<<<N_EDGES/256,256,0,stream>>>(src,dst,cursor,csrsrc);
  prep_bf16_kernel<<<(294912+612+255)/256,256,0,stream>>>(lem_hid_w,lem_z_w,mlp1_w,mlp2_w,
                                                      gate_lin_w,gnn_lin_w,
                                                      gate_edge_w,gnn_edge_w,gate_att_edge,gnn_att_edge,
                                                      whb,wzb,w1b,w2b,wlin16,wearr);
  gsc_kernel<<<N_NODES/128,128,0,stream>>>(u,pos,wearr,gsc);

  short* xtbuf[2]={xtA,xtB};
  float* ssbuf[2]={ssA,ssB};
  float* sdbuf[2]={sdA,sdB};

  lem_t0_kernel<<<N_NODES/32,512,0,stream>>>(u,pos,lem_inp_w,lem_inp_b,whb,lem_hid_b,
      wzb,lem_z_b,w1b,mlp1_b,w2b,mlp2_b,h,
      wlin16,
      gate_att_src, gate_att_dst, gnn_att_src, gnn_att_dst,
      gsc, gsc+(size_t)N_NODES,
      xtbuf[0], ssbuf[0], sdbuf[0]);

  for(int l=0;l<5;++l){
    int in=l&1, o2=(l+1)&1;
    gat_fused_kernel<<<N_NODES/16,512,0,stream>>>(rowptr,csrsrc,
      xtbuf[in],ssbuf[in],sdbuf[in],
      gate_bias+l*128, gnn_bias+l*128, h,
      wlin16+(size_t)(l+1)*2*16384,
      gate_att_src+(l+1)*128, gate_att_dst+(l+1)*128,
      gnn_att_src+(l+1)*128, gnn_att_dst+(l+1)*128,
      gsc+(size_t)(2*(l+1))*N_NODES, gsc+(size_t)(2*(l+1)+1)*N_NODES,
      xtbuf[o2], ssbuf[o2], sdbuf[o2]);
  }

  gat_last_decoder_kernel<<<N_NODES/16,512,0,stream>>>(rowptr,csrsrc,
      xtbuf[1],ssbuf[1],sdbuf[1],
      gate_bias+5*128, gnn_bias+5*128, h, u,
      dbl_w, dbl_b, conv1_w, conv1_b, conv2_w, conv2_b, out);
}